// Round 1
// 235.266 us; speedup vs baseline: 1.0147x; 1.0147x over previous
//
#include <hip/hip_runtime.h>
#include <math.h>

// ---------------------------------------------------------------------------
// CausalSelfAttention fused pipeline, MI355X gfx950.  Round 11.
// r10: fast sincos fixed the RoPE epilogue (98->76us QKV GEMM); counters now
// show MfmaUtil 12.5%, VALUBusy 18%, HBM 11% -> K-loop structure-bound.
// r11: replace reg-staging (4 glb loads + 4 ds_writes + 2 barriers/K-step,
// single-buffered) with global_load_lds width=16 into double-buffered LDS,
// one barrier per K-step (T3 minimum 2-phase). The staging layout was already
// fragment-order (pre-swizzled global addrs + linear LDS) which is exactly
// what global_load_lds's wave-uniform-base + lane*16 write pattern needs.
// Evidence: m151 gload_lds 874 vs reg-staging 646 TF at 128^2 tile.
// Workspace: q(=y) 8MB | k 8MB | vt 8MB | xb 8MB | w[4]b 8MB | gate 256KB.
// ---------------------------------------------------------------------------

#define B_    2
#define T_    2048
#define DIM_  1024
#define H_    16
#define HD_   64
#define NROW  (B_ * T_)
#define EPS_  1.1920929e-07f
#define SCALE_ 0.1f
#define LOG2_10K 13.287712379549449f
#define INV2PI 0.15915494309189535f

typedef unsigned short u16;
typedef unsigned int   u32;
typedef __bf16 bf16x8 __attribute__((ext_vector_type(8)));
typedef __bf16 bf16x2 __attribute__((ext_vector_type(2)));
typedef float  f32x4  __attribute__((ext_vector_type(4)));

__device__ __forceinline__ u16 f2b(float f) {
  u32 u = __float_as_uint(f);
  u += 0x7fffu + ((u >> 16) & 1u);       // RNE
  return (u16)(u >> 16);
}
__device__ __forceinline__ u32 pk2(float a, float b) {
#if __has_builtin(__builtin_amdgcn_cvt_pk_bf16_f32)
  bf16x2 r = __builtin_amdgcn_cvt_pk_bf16_f32(a, b);
  return __builtin_bit_cast(u32, r);
#else
  return (u32)f2b(a) | ((u32)f2b(b) << 16);
#endif
}
// fast sin/cos of (rev revolutions): fract to [0,1), then v_sin/v_cos
__device__ __forceinline__ void fast_sincos_rev(float rev, float* s, float* c) {
  const float r = rev - floorf(rev);
#if __has_builtin(__builtin_amdgcn_sinf) && __has_builtin(__builtin_amdgcn_cosf)
  *s = __builtin_amdgcn_sinf(r);
  *c = __builtin_amdgcn_cosf(r);
#else
  *s = __sinf(r * 6.283185307179586f);
  *c = __cosf(r * 6.283185307179586f);
#endif
}
#define MFMA16(a,b,c) __builtin_amdgcn_mfma_f32_16x16x32_bf16((a),(b),(c),0,0,0)

// async global -> LDS, 16B per lane. LDS dest must be wave-uniform base;
// HW writes lane i at base + i*16. Global src is per-lane.
typedef const __attribute__((address_space(1))) unsigned char gbuf_t;
typedef __attribute__((address_space(3))) unsigned char lbuf_t;
__device__ __forceinline__ void gload_lds16(const u16* g, unsigned char* l) {
  __builtin_amdgcn_global_load_lds((gbuf_t*)g, (lbuf_t*)l, 16, 0, 0);
}

// ---------------------------------------------------------------------------
// Convert pass: x (4M) and Wq/Wk/Wv/Wp (1M each) f32 -> bf16.
// ---------------------------------------------------------------------------
__global__ __launch_bounds__(256) void convert_all(
    const float* __restrict__ x, const float* __restrict__ Wq,
    const float* __restrict__ Wk, const float* __restrict__ Wv,
    const float* __restrict__ Wp,
    u16* __restrict__ xb, u16* __restrict__ wb /* wqb|wkb|wvb|wpb */) {
  const int i = blockIdx.x * 256 + threadIdx.x;       // 0 .. 2M-1 groups
  const float* src;
  u16* dst;
  int off;
  if (i < 1048576)       { src = x;  dst = xb;            off = i; }
  else if (i < 1310720)  { src = Wq; dst = wb;            off = i - 1048576; }
  else if (i < 1572864)  { src = Wk; dst = wb + 1048576;  off = i - 1310720; }
  else if (i < 1835008)  { src = Wv; dst = wb + 2097152;  off = i - 1572864; }
  else                   { src = Wp; dst = wb + 3145728;  off = i - 1835008; }
  const float4 f = ((const float4*)src)[off];
  uint2 o;
  o.x = pk2(f.x, f.y);
  o.y = pk2(f.z, f.w);
  ((uint2*)dst)[off] = o;
}

// ---------------------------------------------------------------------------
// global_load_lds double-buffered GEMM: C[row,n] = sum_k A[row,k]*W[n,k].
// 128x128 block tile, BK=32, 4 waves x (64x64 via 4x4 16x16x32 accs).
// LDS 32KB: 2 x (A 8KB | B 8KB), fragment order. K-loop (2-phase):
//   issue 4x global_load_lds(next tile -> buf^1) / 8 ds_read_b128 + 16 MFMA
//   from buf / syncthreads (drains vmcnt+lgkm) / flip.
// IS_PROJ=false: grid (32,24), mode=by>>3: 0 q(rope) 1 k(rope) 2 v(blend,
//   transposed [bh][d][t] store); W = Wb + mode*1M.
// IS_PROJ=true: grid (32,8), W=Wb, f32 out.
// ---------------------------------------------------------------------------
template <bool IS_PROJ>
__global__ __launch_bounds__(256) void gemm_rp(
    const u16* __restrict__ Ab, const u16* __restrict__ Wb,
    u16* __restrict__ qo, u16* __restrict__ ko, u16* __restrict__ vto,
    float* __restrict__ fo, const float* __restrict__ v1,
    const float* __restrict__ lambp) {
  __shared__ __attribute__((aligned(16))) unsigned char sm[32768];
  const int tid  = threadIdx.x;
  const int w    = tid >> 6;
  const int lane = tid & 63;
  const int lo = lane & 15, hi = lane >> 4;
  const int m0 = blockIdx.x << 7;
  const int by = blockIdx.y;
  const int mode = IS_PROJ ? 3 : (by >> 3);
  const int n0 = IS_PROJ ? (by << 7) : ((by & 7) << 7);
  const u16* W = IS_PROJ ? Wb : (Wb + (size_t)mode * (DIM_ * DIM_));

  const int wm = w & 1, wn = w >> 1;

  // per-lane global srcs in fragment order (row = blk*16+lo, kchunk = hi*8)
  const u16* agA0 = Ab + (size_t)(m0 + (2 * w + 0) * 16 + lo) * DIM_ + (hi << 3);
  const u16* agA1 = Ab + (size_t)(m0 + (2 * w + 1) * 16 + lo) * DIM_ + (hi << 3);
  const u16* agB0 = W  + (size_t)(n0 + (2 * w + 0) * 16 + lo) * DIM_ + (hi << 3);
  const u16* agB1 = W  + (size_t)(n0 + (2 * w + 1) * 16 + lo) * DIM_ + (hi << 3);

  f32x4 acc[4][4];
#pragma unroll
  for (int i = 0; i < 4; ++i)
#pragma unroll
    for (int j = 0; j < 4; ++j) acc[i][j] = (f32x4){0.f, 0.f, 0.f, 0.f};

  // prologue: stage K-tile 0 into buf0
  {
    unsigned char* ad = sm + (2 * w) * 1024;
    unsigned char* bd = sm + 8192 + (2 * w) * 1024;
    gload_lds16(agA0, ad);
    gload_lds16(agA1, ad + 1024);
    gload_lds16(agB0, bd);
    gload_lds16(agB1, bd + 1024);
    agA0 += 32; agA1 += 32; agB0 += 32; agB1 += 32;
  }
  __syncthreads();   // waits vmcnt(0) lgkmcnt(0) then s_barrier

  int buf = 0;
  for (int kc = 0; kc < DIM_; kc += 32) {
    if (kc + 32 < DIM_) {
      // issue next K-tile into the other buffer (stays in flight over MFMA)
      unsigned char* ad = sm + ((buf ^ 1) << 14) + (2 * w) * 1024;
      unsigned char* bd = ad + 8192;
      gload_lds16(agA0, ad);
      gload_lds16(agA1, ad + 1024);
      gload_lds16(agB0, bd);
      gload_lds16(agB1, bd + 1024);
      agA0 += 32; agA1 += 32; agB0 += 32; agB1 += 32;
    }
    const unsigned char* Acur = sm + (buf << 14);
    const unsigned char* Bcur = Acur + 8192;
    bf16x8 bfr[4];
#pragma unroll
    for (int nt = 0; nt < 4; ++nt)
      bfr[nt] = *(const bf16x8*)(Bcur + (((wn * 4 + nt) * 64 + lane) << 4));
#pragma unroll
    for (int mt = 0; mt < 4; ++mt) {
      const bf16x8 af = *(const bf16x8*)(Acur + (((wm * 4 + mt) * 64 + lane) << 4));
#pragma unroll
      for (int nt = 0; nt < 4; ++nt)
        acc[mt][nt] = MFMA16(af, bfr[nt], acc[mt][nt]);
    }
    if (kc + 32 < DIM_) __syncthreads();   // drain staged loads + flip
    buf ^= 1;
  }

  // ---- register epilogues ----
  const int head = (n0 >> 6) + wn;
  if (mode <= 1) {
    u16* C = (mode == 0) ? qo : ko;
    // frequencies in REVOLUTIONS (1/2pi folded in)
    const float if0 = exp2f(-(float)lo * (LOG2_10K / 32.f)) * INV2PI;
    const float if1 = exp2f(-(float)(lo + 16) * (LOG2_10K / 32.f)) * INV2PI;
#pragma unroll
    for (int mt = 0; mt < 4; ++mt)
#pragma unroll
      for (int r = 0; r < 4; ++r) {
        float ss = 0.f;
#pragma unroll
        for (int nt = 0; nt < 4; ++nt) { const float v = acc[mt][nt][r]; ss += v * v; }
        ss += __shfl_xor(ss, 1, 64); ss += __shfl_xor(ss, 2, 64);
        ss += __shfl_xor(ss, 4, 64); ss += __shfl_xor(ss, 8, 64);
        const float scl = rsqrtf(ss * (1.f / 64.f) + EPS_);
        const int row_g = m0 + wm * 64 + mt * 16 + hi * 4 + r;
        const float tpos = (float)(row_g & (T_ - 1));
        float sn0, cs0, sn1, cs1;
        fast_sincos_rev(tpos * if0, &sn0, &cs0);
        fast_sincos_rev(tpos * if1, &sn1, &cs1);
        u16* crow = C + (size_t)row_g * DIM_ + head * HD_;
        const float x10 = acc[mt][0][r] * scl, x11 = acc[mt][1][r] * scl;
        const float x20 = acc[mt][2][r] * scl, x21 = acc[mt][3][r] * scl;
        crow[lo]      = f2b(x10 * cs0 + x20 * sn0);
        crow[16 + lo] = f2b(x11 * cs1 + x21 * sn1);
        crow[32 + lo] = f2b(x20 * cs0 - x10 * sn0);
        crow[48 + lo] = f2b(x21 * cs1 - x11 * sn1);
      }
  } else if (mode == 2) {
    const float lam = lambp[0];
#pragma unroll
    for (int mt = 0; mt < 4; ++mt)
#pragma unroll
      for (int r = 0; r < 4; ++r) {
        const int row_g = m0 + wm * 64 + mt * 16 + hi * 4 + r;
        const int bb = row_g >> 11, tt = row_g & (T_ - 1);
        const int bh = bb * H_ + head;
        const float* v1r = v1 + (size_t)row_g * DIM_ + head * HD_;
#pragma unroll
        for (int nt = 0; nt < 4; ++nt) {
          const int d = nt * 16 + lo;
          const float ov = (1.f - lam) * acc[mt][nt][r] + lam * v1r[d];
          vto[((size_t)(bh * HD_ + d)) * T_ + tt] = f2b(ov);   // transposed
        }
      }
  } else {
#pragma unroll
    for (int mt = 0; mt < 4; ++mt)
#pragma unroll
      for (int r = 0; r < 4; ++r) {
        const int row_g = m0 + wm * 64 + mt * 16 + hi * 4 + r;
        float* orow = fo + (size_t)row_g * DIM_ + n0 + wn * 64;
#pragma unroll
        for (int nt = 0; nt < 4; ++nt) orow[nt * 16 + lo] = acc[mt][nt][r];
      }
  }
}

// ---------------------------------------------------------------------------
// gate[n,h] = sigmoid( sum_{j<12} x[n,j]*Wg[h,j] )
// ---------------------------------------------------------------------------
__global__ __launch_bounds__(256) void gate_kernel(
    const float* __restrict__ x, const float* __restrict__ Wg,
    float* __restrict__ gate) {
  const int id = blockIdx.x * 256 + threadIdx.x;
  const int n = id >> 4, h = id & 15;
  const float* xr = x + (size_t)n * DIM_;
  const float* wr = Wg + h * 12;
  float s = 0.f;
#pragma unroll
  for (int j = 0; j < 12; ++j) s += xr[j] * wr[j];
  gate[id] = 1.f / (1.f + __expf(-s));
}

// ---------------------------------------------------------------------------
// MFMA flash attention, S^T form (r6-verified). Block = (b,h,64-q tile).
// ---------------------------------------------------------------------------
__global__ __launch_bounds__(256) void attn3(
    const u16* __restrict__ q, const u16* __restrict__ k, const u16* __restrict__ vt,
    const float* __restrict__ gate, u16* __restrict__ y) {
  __shared__ __attribute__((aligned(16))) unsigned char smem[16384];
  const int tid = threadIdx.x;
  const int wv = tid >> 6, lane = tid & 63, lo = lane & 15, hi = lane >> 4;
  const int idx = blockIdx.x;
  const int qt = 31 - (idx >> 5);
  const int bh = idx & 31;
  const int b = bh >> 4, h = bh & 15;
  const int qb = qt << 6;

  const int qrow = b * T_ + qb + wv * 16 + lo;
  const u16* qp = q + (size_t)qrow * DIM_ + h * HD_;
  const bf16x8 qf0 = *(const bf16x8*)(qp + hi * 8);
  const bf16x8 qf1 = *(const bf16x8*)(qp + 32 + hi * 8);

  f32x4 o[4];
#pragma unroll
  for (int i = 0; i < 4; ++i) o[i] = (f32x4){0.f, 0.f, 0.f, 0.f};
  float mrun = -1e30f, lrun = 0.f;

  const int sl = tid & 63, skh = (tid >> 6) & 1, st0 = tid >> 7;
  const int srow = sl & 15, skk = skh * 32 + ((sl >> 4) << 3);
  const u16* kg0 = k + ((size_t)(b * T_ + st0 * 16 + srow)) * DIM_ + h * HD_ + skk;
  const u16* kg1 = kg0 + (size_t)32 * DIM_;
  const u16* vg0 = vt + ((size_t)(bh * HD_ + st0 * 16 + srow)) * T_ + skk;
  const u16* vg1 = vg0 + (size_t)32 * T_;

  uint4 kr0 = *(const uint4*)kg0, kr1 = *(const uint4*)kg1;
  uint4 vr0 = *(const uint4*)vg0, vr1 = *(const uint4*)vg1;

  const int off0 = tid << 4, off1 = (tid + 256) << 4;

  for (int tix = 0; tix <= qt; ++tix) {
    __syncthreads();
    *(uint4*)(smem + off0) = kr0;
    *(uint4*)(smem + off1) = kr1;
    *(uint4*)(smem + 8192 + off0) = vr0;
    *(uint4*)(smem + 8192 + off1) = vr1;
    if (tix < qt) {
      const size_t ko = (size_t)(tix + 1) * 64 * DIM_;
      const size_t vo = (size_t)(tix + 1) * 64;
      kr0 = *(const uint4*)(kg0 + ko); kr1 = *(const uint4*)(kg1 + ko);
      vr0 = *(const uint4*)(vg0 + vo); vr1 = *(const uint4*)(vg1 + vo);
    }
    __syncthreads();

    f32x4 stl[4];
#pragma unroll
    for (int kt = 0; kt < 4; ++kt) stl[kt] = (f32x4){0.f, 0.f, 0.f, 0.f};
#pragma unroll
    for (int kh = 0; kh < 2; ++kh) {
      const bf16x8 qb_ = kh ? qf1 : qf0;
#pragma unroll
      for (int kt = 0; kt < 4; ++kt) {
        const bf16x8 af = *(const bf16x8*)(smem + (((kt * 2 + kh) * 64 + lane) << 4));
        stl[kt] = MFMA16(af, qb_, stl[kt]);
      }
    }
    const bool diag = (tix == qt);
#pragma unroll
    for (int kt = 0; kt < 4; ++kt)
#pragma unroll
      for (int r = 0; r < 4; ++r) {
        float s = stl[kt][r] * SCALE_;
        if (diag && (kt * 16 + hi * 4 + r > wv * 16 + lo)) s = -3e38f;
        stl[kt][r] = s;
      }
    float mx = stl[0][0];
#pragma unroll
    for (int kt = 0; kt < 4; ++kt)
#pragma unroll
      for (int r = 0; r < 4; ++r) mx = fmaxf(mx, stl[kt][r]);
    mx = fmaxf(mx, __shfl_xor(mx, 16, 64));
    mx = fmaxf(mx, __shfl_xor(mx, 32, 64));
    const float mn = fmaxf(mrun, mx);
    const float alpha = __expf(mrun - mn);
    mrun = mn;
    float ps = 0.f;
#pragma unroll
    for (int kt = 0; kt < 4; ++kt)
#pragma unroll
      for (int r = 0; r < 4; ++r) { stl[kt][r] = __expf(stl[kt][r] - mn); ps += stl[kt][r]; }
    ps += __shfl_xor(ps, 16, 64);
    ps += __shfl_xor(ps, 32, 64);
    lrun = lrun * alpha + ps;
#pragma unroll
    for (int dt = 0; dt < 4; ++dt) o[dt] *= alpha;

    u32 pkv[4][2];
#pragma unroll
    for (int kt = 0; kt < 4; ++kt) {
      pkv[kt][0] = pk2(stl[kt][0], stl[kt][1]);
      pkv[kt][1] = pk2(stl[kt][2], stl[kt][3]);
    }
#pragma unroll
    for (int kh = 0; kh < 2; ++kh) {
      uint4 w4;
      u32* w4p = (u32*)&w4;
#pragma unroll
      for (int wd = 0; wd < 4; ++wd) {
        const int src = (2 * (hi & 1) + (wd >> 1)) * 16 + lo;
        const u32 a  = (u32)__shfl((int)pkv[2 * kh][wd & 1], src, 64);
        const u32 bb = (u32)__shfl((int)pkv[2 * kh + 1][wd & 1], src, 64);
        w4p[wd] = (hi < 2) ? a : bb;
      }
      const bf16x8 pf = __builtin_bit_cast(bf16x8, w4);
#pragma unroll
      for (int dt = 0; dt < 4; ++dt) {
        const bf16x8 vf = *(const bf16x8*)(smem + 8192 + (((dt * 2 + kh) * 64 + lane) << 4));
        o[dt] = MFMA16(vf, pf, o[dt]);
      }
    }
  }

  const float inv = gate[(size_t)qrow * H_ + h] / lrun;
  u16* yrow = y + (size_t)qrow * DIM_ + h * HD_;
#pragma unroll
  for (int dt = 0; dt < 4; ++dt) {
    ushort4 pq;
    pq.x = f2b(o[dt][0] * inv); pq.y = f2b(o[dt][1] * inv);
    pq.z = f2b(o[dt][2] * inv); pq.w = f2b(o[dt][3] * inv);
    *(ushort4*)(yrow + dt * 16 + hi * 4) = pq;
  }
}

// ---------------------------------------------------------------------------
extern "C" void kernel_launch(void* const* d_in, const int* in_sizes, int n_in,
                              void* d_out, int out_size, void* d_ws, size_t ws_size,
                              hipStream_t stream) {
  const float* x    = (const float*)d_in[0];
  const float* v1   = (const float*)d_in[1];
  const float* Wq   = (const float*)d_in[2];
  const float* Wk   = (const float*)d_in[3];
  const float* Wv   = (const float*)d_in[4];
  const float* Wp   = (const float*)d_in[5];
  const float* Wg   = (const float*)d_in[6];
  const float* lamb = (const float*)d_in[7];

  const size_t NX = (size_t)NROW * DIM_;        // 4M
  const size_t NW = (size_t)DIM_ * DIM_;        // 1M

  u16* q  = (u16*)d_ws;                         // also y (in-place)
  u16* k  = q + NX;
  u16* vt = k + NX;                             // [bh][d][t]
  u16* xb = vt + NX;
  u16* wb = xb + NX;                            // wqb|wkb|wvb|wpb (4M)
  float* gate = (float*)(wb + 4 * NW);          // total ws: 40.25 MB

  const dim3 bb(256);

  convert_all<<<dim3(8192), bb, 0, stream>>>(x, Wq, Wk, Wv, Wp, xb, wb);
  gemm_rp<false><<<dim3(NROW / 128, 24), bb, 0, stream>>>(
      xb, wb, q, k, vt, nullptr, v1, lamb);
  gate_kernel<<<dim3(NROW * H_ / 256), bb, 0, stream>>>(x, Wg, gate);
  attn3<<<dim3(B_ * H_ * (T_ / 64)), bb, 0, stream>>>(q, k, vt, gate, q);
  gemm_rp<true><<<dim3(NROW / 128, 8), bb, 0, stream>>>(
      q, wb + 3 * NW, nullptr, nullptr, nullptr, (float*)d_out, nullptr, nullptr);
}

// Round 2
// 226.309 us; speedup vs baseline: 1.0548x; 1.0396x over previous
//
#include <hip/hip_runtime.h>
#include <math.h>

// ---------------------------------------------------------------------------
// CausalSelfAttention fused pipeline, MI355X gfx950.  Round 12.
// r11 post-mortem: gload_lds + 2-phase dbuf removed staging VALU (18->10%)
// but dur unchanged -> K-loop is WAIT-bound: per-step __syncthreads drains
// vmcnt(0) ~200cy after issue; 3 lockstep blocks/CU can't fill the stall
// (Mfma 13 + VALU 10 = 23% busy). r12: T4 counted-vmcnt deep prefetch:
// triple-buffered LDS (48KB), depth-2 prefetch, raw s_barrier +
// s_waitcnt vmcnt(4) (drains tile issued TWO steps ago; never 0 until the
// final step). sched_barrier(0) pins ds_read/MFMA motion across the barrier
// (guide rule #18). Buffer hazard: step c overwrites buf (c-1)%3, last read
// at step c-1, protected by barrier c.
// Workspace: q(=y) 8MB | k 8MB | vt 8MB | xb 8MB | w[4]b 8MB | gate 256KB.
// ---------------------------------------------------------------------------

#define B_    2
#define T_    2048
#define DIM_  1024
#define H_    16
#define HD_   64
#define NROW  (B_ * T_)
#define EPS_  1.1920929e-07f
#define SCALE_ 0.1f
#define LOG2_10K 13.287712379549449f
#define INV2PI 0.15915494309189535f

typedef unsigned short u16;
typedef unsigned int   u32;
typedef __bf16 bf16x8 __attribute__((ext_vector_type(8)));
typedef __bf16 bf16x2 __attribute__((ext_vector_type(2)));
typedef float  f32x4  __attribute__((ext_vector_type(4)));

__device__ __forceinline__ u16 f2b(float f) {
  u32 u = __float_as_uint(f);
  u += 0x7fffu + ((u >> 16) & 1u);       // RNE
  return (u16)(u >> 16);
}
__device__ __forceinline__ u32 pk2(float a, float b) {
#if __has_builtin(__builtin_amdgcn_cvt_pk_bf16_f32)
  bf16x2 r = __builtin_amdgcn_cvt_pk_bf16_f32(a, b);
  return __builtin_bit_cast(u32, r);
#else
  return (u32)f2b(a) | ((u32)f2b(b) << 16);
#endif
}
// fast sin/cos of (rev revolutions): fract to [0,1), then v_sin/v_cos
__device__ __forceinline__ void fast_sincos_rev(float rev, float* s, float* c) {
  const float r = rev - floorf(rev);
#if __has_builtin(__builtin_amdgcn_sinf) && __has_builtin(__builtin_amdgcn_cosf)
  *s = __builtin_amdgcn_sinf(r);
  *c = __builtin_amdgcn_cosf(r);
#else
  *s = __sinf(r * 6.283185307179586f);
  *c = __cosf(r * 6.283185307179586f);
#endif
}
#define MFMA16(a,b,c) __builtin_amdgcn_mfma_f32_16x16x32_bf16((a),(b),(c),0,0,0)

// async global -> LDS, 16B per lane. LDS dest must be wave-uniform base;
// HW writes lane i at base + i*16. Global src is per-lane.
typedef const __attribute__((address_space(1))) unsigned char gbuf_t;
typedef __attribute__((address_space(3))) unsigned char lbuf_t;
__device__ __forceinline__ void gload_lds16(const u16* g, unsigned char* l) {
  __builtin_amdgcn_global_load_lds((gbuf_t*)g, (lbuf_t*)l, 16, 0, 0);
}

// ---------------------------------------------------------------------------
// Convert pass: x (4M) and Wq/Wk/Wv/Wp (1M each) f32 -> bf16.
// ---------------------------------------------------------------------------
__global__ __launch_bounds__(256) void convert_all(
    const float* __restrict__ x, const float* __restrict__ Wq,
    const float* __restrict__ Wk, const float* __restrict__ Wv,
    const float* __restrict__ Wp,
    u16* __restrict__ xb, u16* __restrict__ wb /* wqb|wkb|wvb|wpb */) {
  const int i = blockIdx.x * 256 + threadIdx.x;       // 0 .. 2M-1 groups
  const float* src;
  u16* dst;
  int off;
  if (i < 1048576)       { src = x;  dst = xb;            off = i; }
  else if (i < 1310720)  { src = Wq; dst = wb;            off = i - 1048576; }
  else if (i < 1572864)  { src = Wk; dst = wb + 1048576;  off = i - 1310720; }
  else if (i < 1835008)  { src = Wv; dst = wb + 2097152;  off = i - 1572864; }
  else                   { src = Wp; dst = wb + 3145728;  off = i - 1835008; }
  const float4 f = ((const float4*)src)[off];
  uint2 o;
  o.x = pk2(f.x, f.y);
  o.y = pk2(f.z, f.w);
  ((uint2*)dst)[off] = o;
}

// ---------------------------------------------------------------------------
// Deep-prefetch GEMM: C[row,n] = sum_k A[row,k]*W[n,k].
// 128x128 block tile, BK=32, 4 waves x (64x64 via 4x4 16x16x32 accs).
// LDS 48KB: 3 x (A 8KB | B 8KB) ring, fragment order. K-loop per step c:
//   sched_barrier / s_waitcnt vmcnt(4) [L(c) done, L(c+1) in flight] /
//   s_barrier / issue 4x global_load_lds L(c+2) -> buf (c+2)%3 /
//   8 ds_read_b128 + 16 MFMA from buf c%3.
// IS_PROJ=false: grid (32,24), mode=by>>3: 0 q(rope) 1 k(rope) 2 v(blend,
//   transposed [bh][d][t] store); W = Wb + mode*1M.
// IS_PROJ=true: grid (32,8), W=Wb, f32 out.
// ---------------------------------------------------------------------------
template <bool IS_PROJ>
__global__ __launch_bounds__(256) void gemm_rp(
    const u16* __restrict__ Ab, const u16* __restrict__ Wb,
    u16* __restrict__ qo, u16* __restrict__ ko, u16* __restrict__ vto,
    float* __restrict__ fo, const float* __restrict__ v1,
    const float* __restrict__ lambp) {
  __shared__ __attribute__((aligned(16))) unsigned char sm[49152];
  const int tid  = threadIdx.x;
  const int w    = tid >> 6;
  const int lane = tid & 63;
  const int lo = lane & 15, hi = lane >> 4;
  const int m0 = blockIdx.x << 7;
  const int by = blockIdx.y;
  const int mode = IS_PROJ ? 3 : (by >> 3);
  const int n0 = IS_PROJ ? (by << 7) : ((by & 7) << 7);
  const u16* W = IS_PROJ ? Wb : (Wb + (size_t)mode * (DIM_ * DIM_));

  const int wm = w & 1, wn = w >> 1;

  // per-lane global srcs in fragment order (row = blk*16+lo, kchunk = hi*8)
  const u16* agA0 = Ab + (size_t)(m0 + (2 * w + 0) * 16 + lo) * DIM_ + (hi << 3);
  const u16* agA1 = Ab + (size_t)(m0 + (2 * w + 1) * 16 + lo) * DIM_ + (hi << 3);
  const u16* agB0 = W  + (size_t)(n0 + (2 * w + 0) * 16 + lo) * DIM_ + (hi << 3);
  const u16* agB1 = W  + (size_t)(n0 + (2 * w + 1) * 16 + lo) * DIM_ + (hi << 3);

  f32x4 acc[4][4];
#pragma unroll
  for (int i = 0; i < 4; ++i)
#pragma unroll
    for (int j = 0; j < 4; ++j) acc[i][j] = (f32x4){0.f, 0.f, 0.f, 0.f};

  // prologue: stage K-tiles 0 and 1 into bufs 0 and 1 (8 loads in flight)
  {
    unsigned char* ad0 = sm + (2 * w) * 1024;
    gload_lds16(agA0, ad0);
    gload_lds16(agA1, ad0 + 1024);
    gload_lds16(agB0, ad0 + 8192);
    gload_lds16(agB1, ad0 + 9216);
    agA0 += 32; agA1 += 32; agB0 += 32; agB1 += 32;
    unsigned char* ad1 = sm + 16384 + (2 * w) * 1024;
    gload_lds16(agA0, ad1);
    gload_lds16(agA1, ad1 + 1024);
    gload_lds16(agB0, ad1 + 8192);
    gload_lds16(agB1, ad1 + 9216);
    agA0 += 32; agA1 += 32; agB0 += 32; agB1 += 32;
  }

  int cr = 0;   // read buffer  (= c % 3)
  int cw = 2;   // write buffer (= (c+2) % 3)
  for (int kc = 0; kc < DIM_; kc += 32) {
    __builtin_amdgcn_sched_barrier(0);
    if (kc + 32 < DIM_) {
      asm volatile("s_waitcnt vmcnt(4)" ::: "memory");  // L(c) landed
    } else {
      asm volatile("s_waitcnt vmcnt(0)" ::: "memory");  // last tile
    }
    __builtin_amdgcn_s_barrier();
    __builtin_amdgcn_sched_barrier(0);
    if (kc + 64 < DIM_) {
      // issue L(c+2) into ring buffer cw (last read at step c-1, barrier-safe)
      unsigned char* ad = sm + cw * 16384 + (2 * w) * 1024;
      gload_lds16(agA0, ad);
      gload_lds16(agA1, ad + 1024);
      gload_lds16(agB0, ad + 8192);
      gload_lds16(agB1, ad + 9216);
      agA0 += 32; agA1 += 32; agB0 += 32; agB1 += 32;
    }
    const unsigned char* Acur = sm + cr * 16384;
    const unsigned char* Bcur = Acur + 8192;
    bf16x8 bfr[4];
#pragma unroll
    for (int nt = 0; nt < 4; ++nt)
      bfr[nt] = *(const bf16x8*)(Bcur + (((wn * 4 + nt) * 64 + lane) << 4));
#pragma unroll
    for (int mt = 0; mt < 4; ++mt) {
      const bf16x8 af = *(const bf16x8*)(Acur + (((wm * 4 + mt) * 64 + lane) << 4));
#pragma unroll
      for (int nt = 0; nt < 4; ++nt)
        acc[mt][nt] = MFMA16(af, bfr[nt], acc[mt][nt]);
    }
    cr = (cr == 2) ? 0 : cr + 1;
    cw = (cw == 2) ? 0 : cw + 1;
  }

  // ---- register epilogues ----
  const int head = (n0 >> 6) + wn;
  if (mode <= 1) {
    u16* C = (mode == 0) ? qo : ko;
    // frequencies in REVOLUTIONS (1/2pi folded in)
    const float if0 = exp2f(-(float)lo * (LOG2_10K / 32.f)) * INV2PI;
    const float if1 = exp2f(-(float)(lo + 16) * (LOG2_10K / 32.f)) * INV2PI;
#pragma unroll
    for (int mt = 0; mt < 4; ++mt)
#pragma unroll
      for (int r = 0; r < 4; ++r) {
        float ss = 0.f;
#pragma unroll
        for (int nt = 0; nt < 4; ++nt) { const float v = acc[mt][nt][r]; ss += v * v; }
        ss += __shfl_xor(ss, 1, 64); ss += __shfl_xor(ss, 2, 64);
        ss += __shfl_xor(ss, 4, 64); ss += __shfl_xor(ss, 8, 64);
        const float scl = rsqrtf(ss * (1.f / 64.f) + EPS_);
        const int row_g = m0 + wm * 64 + mt * 16 + hi * 4 + r;
        const float tpos = (float)(row_g & (T_ - 1));
        float sn0, cs0, sn1, cs1;
        fast_sincos_rev(tpos * if0, &sn0, &cs0);
        fast_sincos_rev(tpos * if1, &sn1, &cs1);
        u16* crow = C + (size_t)row_g * DIM_ + head * HD_;
        const float x10 = acc[mt][0][r] * scl, x11 = acc[mt][1][r] * scl;
        const float x20 = acc[mt][2][r] * scl, x21 = acc[mt][3][r] * scl;
        crow[lo]      = f2b(x10 * cs0 + x20 * sn0);
        crow[16 + lo] = f2b(x11 * cs1 + x21 * sn1);
        crow[32 + lo] = f2b(x20 * cs0 - x10 * sn0);
        crow[48 + lo] = f2b(x21 * cs1 - x11 * sn1);
      }
  } else if (mode == 2) {
    const float lam = lambp[0];
#pragma unroll
    for (int mt = 0; mt < 4; ++mt)
#pragma unroll
      for (int r = 0; r < 4; ++r) {
        const int row_g = m0 + wm * 64 + mt * 16 + hi * 4 + r;
        const int bb = row_g >> 11, tt = row_g & (T_ - 1);
        const int bh = bb * H_ + head;
        const float* v1r = v1 + (size_t)row_g * DIM_ + head * HD_;
#pragma unroll
        for (int nt = 0; nt < 4; ++nt) {
          const int d = nt * 16 + lo;
          const float ov = (1.f - lam) * acc[mt][nt][r] + lam * v1r[d];
          vto[((size_t)(bh * HD_ + d)) * T_ + tt] = f2b(ov);   // transposed
        }
      }
  } else {
#pragma unroll
    for (int mt = 0; mt < 4; ++mt)
#pragma unroll
      for (int r = 0; r < 4; ++r) {
        const int row_g = m0 + wm * 64 + mt * 16 + hi * 4 + r;
        float* orow = fo + (size_t)row_g * DIM_ + n0 + wn * 64;
#pragma unroll
        for (int nt = 0; nt < 4; ++nt) orow[nt * 16 + lo] = acc[mt][nt][r];
      }
  }
}

// ---------------------------------------------------------------------------
// gate[n,h] = sigmoid( sum_{j<12} x[n,j]*Wg[h,j] )
// ---------------------------------------------------------------------------
__global__ __launch_bounds__(256) void gate_kernel(
    const float* __restrict__ x, const float* __restrict__ Wg,
    float* __restrict__ gate) {
  const int id = blockIdx.x * 256 + threadIdx.x;
  const int n = id >> 4, h = id & 15;
  const float* xr = x + (size_t)n * DIM_;
  const float* wr = Wg + h * 12;
  float s = 0.f;
#pragma unroll
  for (int j = 0; j < 12; ++j) s += xr[j] * wr[j];
  gate[id] = 1.f / (1.f + __expf(-s));
}

// ---------------------------------------------------------------------------
// MFMA flash attention, S^T form (r6-verified). Block = (b,h,64-q tile).
// ---------------------------------------------------------------------------
__global__ __launch_bounds__(256) void attn3(
    const u16* __restrict__ q, const u16* __restrict__ k, const u16* __restrict__ vt,
    const float* __restrict__ gate, u16* __restrict__ y) {
  __shared__ __attribute__((aligned(16))) unsigned char smem[16384];
  const int tid = threadIdx.x;
  const int wv = tid >> 6, lane = tid & 63, lo = lane & 15, hi = lane >> 4;
  const int idx = blockIdx.x;
  const int qt = 31 - (idx >> 5);
  const int bh = idx & 31;
  const int b = bh >> 4, h = bh & 15;
  const int qb = qt << 6;

  const int qrow = b * T_ + qb + wv * 16 + lo;
  const u16* qp = q + (size_t)qrow * DIM_ + h * HD_;
  const bf16x8 qf0 = *(const bf16x8*)(qp + hi * 8);
  const bf16x8 qf1 = *(const bf16x8*)(qp + 32 + hi * 8);

  f32x4 o[4];
#pragma unroll
  for (int i = 0; i < 4; ++i) o[i] = (f32x4){0.f, 0.f, 0.f, 0.f};
  float mrun = -1e30f, lrun = 0.f;

  const int sl = tid & 63, skh = (tid >> 6) & 1, st0 = tid >> 7;
  const int srow = sl & 15, skk = skh * 32 + ((sl >> 4) << 3);
  const u16* kg0 = k + ((size_t)(b * T_ + st0 * 16 + srow)) * DIM_ + h * HD_ + skk;
  const u16* kg1 = kg0 + (size_t)32 * DIM_;
  const u16* vg0 = vt + ((size_t)(bh * HD_ + st0 * 16 + srow)) * T_ + skk;
  const u16* vg1 = vg0 + (size_t)32 * T_;

  uint4 kr0 = *(const uint4*)kg0, kr1 = *(const uint4*)kg1;
  uint4 vr0 = *(const uint4*)vg0, vr1 = *(const uint4*)vg1;

  const int off0 = tid << 4, off1 = (tid + 256) << 4;

  for (int tix = 0; tix <= qt; ++tix) {
    __syncthreads();
    *(uint4*)(smem + off0) = kr0;
    *(uint4*)(smem + off1) = kr1;
    *(uint4*)(smem + 8192 + off0) = vr0;
    *(uint4*)(smem + 8192 + off1) = vr1;
    if (tix < qt) {
      const size_t ko = (size_t)(tix + 1) * 64 * DIM_;
      const size_t vo = (size_t)(tix + 1) * 64;
      kr0 = *(const uint4*)(kg0 + ko); kr1 = *(const uint4*)(kg1 + ko);
      vr0 = *(const uint4*)(vg0 + vo); vr1 = *(const uint4*)(vg1 + vo);
    }
    __syncthreads();

    f32x4 stl[4];
#pragma unroll
    for (int kt = 0; kt < 4; ++kt) stl[kt] = (f32x4){0.f, 0.f, 0.f, 0.f};
#pragma unroll
    for (int kh = 0; kh < 2; ++kh) {
      const bf16x8 qb_ = kh ? qf1 : qf0;
#pragma unroll
      for (int kt = 0; kt < 4; ++kt) {
        const bf16x8 af = *(const bf16x8*)(smem + (((kt * 2 + kh) * 64 + lane) << 4));
        stl[kt] = MFMA16(af, qb_, stl[kt]);
      }
    }
    const bool diag = (tix == qt);
#pragma unroll
    for (int kt = 0; kt < 4; ++kt)
#pragma unroll
      for (int r = 0; r < 4; ++r) {
        float s = stl[kt][r] * SCALE_;
        if (diag && (kt * 16 + hi * 4 + r > wv * 16 + lo)) s = -3e38f;
        stl[kt][r] = s;
      }
    float mx = stl[0][0];
#pragma unroll
    for (int kt = 0; kt < 4; ++kt)
#pragma unroll
      for (int r = 0; r < 4; ++r) mx = fmaxf(mx, stl[kt][r]);
    mx = fmaxf(mx, __shfl_xor(mx, 16, 64));
    mx = fmaxf(mx, __shfl_xor(mx, 32, 64));
    const float mn = fmaxf(mrun, mx);
    const float alpha = __expf(mrun - mn);
    mrun = mn;
    float ps = 0.f;
#pragma unroll
    for (int kt = 0; kt < 4; ++kt)
#pragma unroll
      for (int r = 0; r < 4; ++r) { stl[kt][r] = __expf(stl[kt][r] - mn); ps += stl[kt][r]; }
    ps += __shfl_xor(ps, 16, 64);
    ps += __shfl_xor(ps, 32, 64);
    lrun = lrun * alpha + ps;
#pragma unroll
    for (int dt = 0; dt < 4; ++dt) o[dt] *= alpha;

    u32 pkv[4][2];
#pragma unroll
    for (int kt = 0; kt < 4; ++kt) {
      pkv[kt][0] = pk2(stl[kt][0], stl[kt][1]);
      pkv[kt][1] = pk2(stl[kt][2], stl[kt][3]);
    }
#pragma unroll
    for (int kh = 0; kh < 2; ++kh) {
      uint4 w4;
      u32* w4p = (u32*)&w4;
#pragma unroll
      for (int wd = 0; wd < 4; ++wd) {
        const int src = (2 * (hi & 1) + (wd >> 1)) * 16 + lo;
        const u32 a  = (u32)__shfl((int)pkv[2 * kh][wd & 1], src, 64);
        const u32 bb = (u32)__shfl((int)pkv[2 * kh + 1][wd & 1], src, 64);
        w4p[wd] = (hi < 2) ? a : bb;
      }
      const bf16x8 pf = __builtin_bit_cast(bf16x8, w4);
#pragma unroll
      for (int dt = 0; dt < 4; ++dt) {
        const bf16x8 vf = *(const bf16x8*)(smem + 8192 + (((dt * 2 + kh) * 64 + lane) << 4));
        o[dt] = MFMA16(vf, pf, o[dt]);
      }
    }
  }

  const float inv = gate[(size_t)qrow * H_ + h] / lrun;
  u16* yrow = y + (size_t)qrow * DIM_ + h * HD_;
#pragma unroll
  for (int dt = 0; dt < 4; ++dt) {
    ushort4 pq;
    pq.x = f2b(o[dt][0] * inv); pq.y = f2b(o[dt][1] * inv);
    pq.z = f2b(o[dt][2] * inv); pq.w = f2b(o[dt][3] * inv);
    *(ushort4*)(yrow + dt * 16 + hi * 4) = pq;
  }
}

// ---------------------------------------------------------------------------
extern "C" void kernel_launch(void* const* d_in, const int* in_sizes, int n_in,
                              void* d_out, int out_size, void* d_ws, size_t ws_size,
                              hipStream_t stream) {
  const float* x    = (const float*)d_in[0];
  const float* v1   = (const float*)d_in[1];
  const float* Wq   = (const float*)d_in[2];
  const float* Wk   = (const float*)d_in[3];
  const float* Wv   = (const float*)d_in[4];
  const float* Wp   = (const float*)d_in[5];
  const float* Wg   = (const float*)d_in[6];
  const float* lamb = (const float*)d_in[7];

  const size_t NX = (size_t)NROW * DIM_;        // 4M
  const size_t NW = (size_t)DIM_ * DIM_;        // 1M

  u16* q  = (u16*)d_ws;                         // also y (in-place)
  u16* k  = q + NX;
  u16* vt = k + NX;                             // [bh][d][t]
  u16* xb = vt + NX;
  u16* wb = xb + NX;                            // wqb|wkb|wvb|wpb (4M)
  float* gate = (float*)(wb + 4 * NW);          // total ws: 40.25 MB

  const dim3 bb(256);

  convert_all<<<dim3(8192), bb, 0, stream>>>(x, Wq, Wk, Wv, Wp, xb, wb);
  gemm_rp<false><<<dim3(NROW / 128, 24), bb, 0, stream>>>(
      xb, wb, q, k, vt, nullptr, v1, lamb);
  gate_kernel<<<dim3(NROW * H_ / 256), bb, 0, stream>>>(x, Wg, gate);
  attn3<<<dim3(B_ * H_ * (T_ / 64)), bb, 0, stream>>>(q, k, vt, gate, q);
  gemm_rp<true><<<dim3(NROW / 128, 8), bb, 0, stream>>>(
      q, wb + 3 * NW, nullptr, nullptr, nullptr, (float*)d_out, nullptr, nullptr);
}

// Round 3
// 221.345 us; speedup vs baseline: 1.0785x; 1.0224x over previous
//
#include <hip/hip_runtime.h>
#include <math.h>

// ---------------------------------------------------------------------------
// CausalSelfAttention fused pipeline, MI355X gfx950.  Round 13.
// r12 post-mortem: QKV GEMM sits on the m102 shape curve (~380 TF at
// M4096/N3072/K1024); MFMA-busy time (9.9us) == pure-MFMA floor (10.3us).
// Structure-at-shape plateau -> stop polishing it. Accounting puts attn3 at
// ~55-65us (cost center #2). r13 attacks attn3:
//  (a) NO-MAX softmax: q,k are RMS-normed (|row|=8, RoPE norm-preserving) so
//      |S| = 0.1|q.k| <= 6.4, exp(S) <= 600, sums <= 1.2e6 -- f32-safe
//      without max subtraction. Deletes the serial fmax chain, 2 shuffle
//      reduces, alpha rescale of o[] between the QK and PV MFMA clusters.
//  (b) T5 s_setprio(1) around both MFMA clusters: attn blocks are
//      independent (4/CU, no lockstep) = the regime where m191 measured
//      +4-7% (GEMM lockstep was null, m190).
// GEMM kernels unchanged from r12 (triple-buffer, counted vmcnt(4)).
// Workspace: q(=y) 8MB | k 8MB | vt 8MB | xb 8MB | w[4]b 8MB | gate 256KB.
// ---------------------------------------------------------------------------

#define B_    2
#define T_    2048
#define DIM_  1024
#define H_    16
#define HD_   64
#define NROW  (B_ * T_)
#define EPS_  1.1920929e-07f
#define SCALE_ 0.1f
#define LOG2_10K 13.287712379549449f
#define INV2PI 0.15915494309189535f

typedef unsigned short u16;
typedef unsigned int   u32;
typedef __bf16 bf16x8 __attribute__((ext_vector_type(8)));
typedef __bf16 bf16x2 __attribute__((ext_vector_type(2)));
typedef float  f32x4  __attribute__((ext_vector_type(4)));

__device__ __forceinline__ u16 f2b(float f) {
  u32 u = __float_as_uint(f);
  u += 0x7fffu + ((u >> 16) & 1u);       // RNE
  return (u16)(u >> 16);
}
__device__ __forceinline__ u32 pk2(float a, float b) {
#if __has_builtin(__builtin_amdgcn_cvt_pk_bf16_f32)
  bf16x2 r = __builtin_amdgcn_cvt_pk_bf16_f32(a, b);
  return __builtin_bit_cast(u32, r);
#else
  return (u32)f2b(a) | ((u32)f2b(b) << 16);
#endif
}
// fast sin/cos of (rev revolutions): fract to [0,1), then v_sin/v_cos
__device__ __forceinline__ void fast_sincos_rev(float rev, float* s, float* c) {
  const float r = rev - floorf(rev);
#if __has_builtin(__builtin_amdgcn_sinf) && __has_builtin(__builtin_amdgcn_cosf)
  *s = __builtin_amdgcn_sinf(r);
  *c = __builtin_amdgcn_cosf(r);
#else
  *s = __sinf(r * 6.283185307179586f);
  *c = __cosf(r * 6.283185307179586f);
#endif
}
#define MFMA16(a,b,c) __builtin_amdgcn_mfma_f32_16x16x32_bf16((a),(b),(c),0,0,0)

// async global -> LDS, 16B per lane. LDS dest must be wave-uniform base;
// HW writes lane i at base + i*16. Global src is per-lane.
typedef const __attribute__((address_space(1))) unsigned char gbuf_t;
typedef __attribute__((address_space(3))) unsigned char lbuf_t;
__device__ __forceinline__ void gload_lds16(const u16* g, unsigned char* l) {
  __builtin_amdgcn_global_load_lds((gbuf_t*)g, (lbuf_t*)l, 16, 0, 0);
}

// ---------------------------------------------------------------------------
// Convert pass: x (4M) and Wq/Wk/Wv/Wp (1M each) f32 -> bf16.
// ---------------------------------------------------------------------------
__global__ __launch_bounds__(256) void convert_all(
    const float* __restrict__ x, const float* __restrict__ Wq,
    const float* __restrict__ Wk, const float* __restrict__ Wv,
    const float* __restrict__ Wp,
    u16* __restrict__ xb, u16* __restrict__ wb /* wqb|wkb|wvb|wpb */) {
  const int i = blockIdx.x * 256 + threadIdx.x;       // 0 .. 2M-1 groups
  const float* src;
  u16* dst;
  int off;
  if (i < 1048576)       { src = x;  dst = xb;            off = i; }
  else if (i < 1310720)  { src = Wq; dst = wb;            off = i - 1048576; }
  else if (i < 1572864)  { src = Wk; dst = wb + 1048576;  off = i - 1310720; }
  else if (i < 1835008)  { src = Wv; dst = wb + 2097152;  off = i - 1572864; }
  else                   { src = Wp; dst = wb + 3145728;  off = i - 1835008; }
  const float4 f = ((const float4*)src)[off];
  uint2 o;
  o.x = pk2(f.x, f.y);
  o.y = pk2(f.z, f.w);
  ((uint2*)dst)[off] = o;
}

// ---------------------------------------------------------------------------
// Deep-prefetch GEMM: C[row,n] = sum_k A[row,k]*W[n,k].
// 128x128 block tile, BK=32, 4 waves x (64x64 via 4x4 16x16x32 accs).
// LDS 48KB: 3 x (A 8KB | B 8KB) ring, fragment order. K-loop per step c:
//   sched_barrier / s_waitcnt vmcnt(4) [L(c) done, L(c+1) in flight] /
//   s_barrier / issue 4x global_load_lds L(c+2) -> buf (c+2)%3 /
//   8 ds_read_b128 + 16 MFMA from buf c%3.
// IS_PROJ=false: grid (32,24), mode=by>>3: 0 q(rope) 1 k(rope) 2 v(blend,
//   transposed [bh][d][t] store); W = Wb + mode*1M.
// IS_PROJ=true: grid (32,8), W=Wb, f32 out.
// ---------------------------------------------------------------------------
template <bool IS_PROJ>
__global__ __launch_bounds__(256) void gemm_rp(
    const u16* __restrict__ Ab, const u16* __restrict__ Wb,
    u16* __restrict__ qo, u16* __restrict__ ko, u16* __restrict__ vto,
    float* __restrict__ fo, const float* __restrict__ v1,
    const float* __restrict__ lambp) {
  __shared__ __attribute__((aligned(16))) unsigned char sm[49152];
  const int tid  = threadIdx.x;
  const int w    = tid >> 6;
  const int lane = tid & 63;
  const int lo = lane & 15, hi = lane >> 4;
  const int m0 = blockIdx.x << 7;
  const int by = blockIdx.y;
  const int mode = IS_PROJ ? 3 : (by >> 3);
  const int n0 = IS_PROJ ? (by << 7) : ((by & 7) << 7);
  const u16* W = IS_PROJ ? Wb : (Wb + (size_t)mode * (DIM_ * DIM_));

  const int wm = w & 1, wn = w >> 1;

  // per-lane global srcs in fragment order (row = blk*16+lo, kchunk = hi*8)
  const u16* agA0 = Ab + (size_t)(m0 + (2 * w + 0) * 16 + lo) * DIM_ + (hi << 3);
  const u16* agA1 = Ab + (size_t)(m0 + (2 * w + 1) * 16 + lo) * DIM_ + (hi << 3);
  const u16* agB0 = W  + (size_t)(n0 + (2 * w + 0) * 16 + lo) * DIM_ + (hi << 3);
  const u16* agB1 = W  + (size_t)(n0 + (2 * w + 1) * 16 + lo) * DIM_ + (hi << 3);

  f32x4 acc[4][4];
#pragma unroll
  for (int i = 0; i < 4; ++i)
#pragma unroll
    for (int j = 0; j < 4; ++j) acc[i][j] = (f32x4){0.f, 0.f, 0.f, 0.f};

  // prologue: stage K-tiles 0 and 1 into bufs 0 and 1 (8 loads in flight)
  {
    unsigned char* ad0 = sm + (2 * w) * 1024;
    gload_lds16(agA0, ad0);
    gload_lds16(agA1, ad0 + 1024);
    gload_lds16(agB0, ad0 + 8192);
    gload_lds16(agB1, ad0 + 9216);
    agA0 += 32; agA1 += 32; agB0 += 32; agB1 += 32;
    unsigned char* ad1 = sm + 16384 + (2 * w) * 1024;
    gload_lds16(agA0, ad1);
    gload_lds16(agA1, ad1 + 1024);
    gload_lds16(agB0, ad1 + 8192);
    gload_lds16(agB1, ad1 + 9216);
    agA0 += 32; agA1 += 32; agB0 += 32; agB1 += 32;
  }

  int cr = 0;   // read buffer  (= c % 3)
  int cw = 2;   // write buffer (= (c+2) % 3)
  for (int kc = 0; kc < DIM_; kc += 32) {
    __builtin_amdgcn_sched_barrier(0);
    if (kc + 32 < DIM_) {
      asm volatile("s_waitcnt vmcnt(4)" ::: "memory");  // L(c) landed
    } else {
      asm volatile("s_waitcnt vmcnt(0)" ::: "memory");  // last tile
    }
    __builtin_amdgcn_s_barrier();
    __builtin_amdgcn_sched_barrier(0);
    if (kc + 64 < DIM_) {
      // issue L(c+2) into ring buffer cw (last read at step c-1, barrier-safe)
      unsigned char* ad = sm + cw * 16384 + (2 * w) * 1024;
      gload_lds16(agA0, ad);
      gload_lds16(agA1, ad + 1024);
      gload_lds16(agB0, ad + 8192);
      gload_lds16(agB1, ad + 9216);
      agA0 += 32; agA1 += 32; agB0 += 32; agB1 += 32;
    }
    const unsigned char* Acur = sm + cr * 16384;
    const unsigned char* Bcur = Acur + 8192;
    bf16x8 bfr[4];
#pragma unroll
    for (int nt = 0; nt < 4; ++nt)
      bfr[nt] = *(const bf16x8*)(Bcur + (((wn * 4 + nt) * 64 + lane) << 4));
#pragma unroll
    for (int mt = 0; mt < 4; ++mt) {
      const bf16x8 af = *(const bf16x8*)(Acur + (((wm * 4 + mt) * 64 + lane) << 4));
#pragma unroll
      for (int nt = 0; nt < 4; ++nt)
        acc[mt][nt] = MFMA16(af, bfr[nt], acc[mt][nt]);
    }
    cr = (cr == 2) ? 0 : cr + 1;
    cw = (cw == 2) ? 0 : cw + 1;
  }

  // ---- register epilogues ----
  const int head = (n0 >> 6) + wn;
  if (mode <= 1) {
    u16* C = (mode == 0) ? qo : ko;
    // frequencies in REVOLUTIONS (1/2pi folded in)
    const float if0 = exp2f(-(float)lo * (LOG2_10K / 32.f)) * INV2PI;
    const float if1 = exp2f(-(float)(lo + 16) * (LOG2_10K / 32.f)) * INV2PI;
#pragma unroll
    for (int mt = 0; mt < 4; ++mt)
#pragma unroll
      for (int r = 0; r < 4; ++r) {
        float ss = 0.f;
#pragma unroll
        for (int nt = 0; nt < 4; ++nt) { const float v = acc[mt][nt][r]; ss += v * v; }
        ss += __shfl_xor(ss, 1, 64); ss += __shfl_xor(ss, 2, 64);
        ss += __shfl_xor(ss, 4, 64); ss += __shfl_xor(ss, 8, 64);
        const float scl = rsqrtf(ss * (1.f / 64.f) + EPS_);
        const int row_g = m0 + wm * 64 + mt * 16 + hi * 4 + r;
        const float tpos = (float)(row_g & (T_ - 1));
        float sn0, cs0, sn1, cs1;
        fast_sincos_rev(tpos * if0, &sn0, &cs0);
        fast_sincos_rev(tpos * if1, &sn1, &cs1);
        u16* crow = C + (size_t)row_g * DIM_ + head * HD_;
        const float x10 = acc[mt][0][r] * scl, x11 = acc[mt][1][r] * scl;
        const float x20 = acc[mt][2][r] * scl, x21 = acc[mt][3][r] * scl;
        crow[lo]      = f2b(x10 * cs0 + x20 * sn0);
        crow[16 + lo] = f2b(x11 * cs1 + x21 * sn1);
        crow[32 + lo] = f2b(x20 * cs0 - x10 * sn0);
        crow[48 + lo] = f2b(x21 * cs1 - x11 * sn1);
      }
  } else if (mode == 2) {
    const float lam = lambp[0];
#pragma unroll
    for (int mt = 0; mt < 4; ++mt)
#pragma unroll
      for (int r = 0; r < 4; ++r) {
        const int row_g = m0 + wm * 64 + mt * 16 + hi * 4 + r;
        const int bb = row_g >> 11, tt = row_g & (T_ - 1);
        const int bh = bb * H_ + head;
        const float* v1r = v1 + (size_t)row_g * DIM_ + head * HD_;
#pragma unroll
        for (int nt = 0; nt < 4; ++nt) {
          const int d = nt * 16 + lo;
          const float ov = (1.f - lam) * acc[mt][nt][r] + lam * v1r[d];
          vto[((size_t)(bh * HD_ + d)) * T_ + tt] = f2b(ov);   // transposed
        }
      }
  } else {
#pragma unroll
    for (int mt = 0; mt < 4; ++mt)
#pragma unroll
      for (int r = 0; r < 4; ++r) {
        const int row_g = m0 + wm * 64 + mt * 16 + hi * 4 + r;
        float* orow = fo + (size_t)row_g * DIM_ + n0 + wn * 64;
#pragma unroll
        for (int nt = 0; nt < 4; ++nt) orow[nt * 16 + lo] = acc[mt][nt][r];
      }
  }
}

// ---------------------------------------------------------------------------
// gate[n,h] = sigmoid( sum_{j<12} x[n,j]*Wg[h,j] )
// ---------------------------------------------------------------------------
__global__ __launch_bounds__(256) void gate_kernel(
    const float* __restrict__ x, const float* __restrict__ Wg,
    float* __restrict__ gate) {
  const int id = blockIdx.x * 256 + threadIdx.x;
  const int n = id >> 4, h = id & 15;
  const float* xr = x + (size_t)n * DIM_;
  const float* wr = Wg + h * 12;
  float s = 0.f;
#pragma unroll
  for (int j = 0; j < 12; ++j) s += xr[j] * wr[j];
  gate[id] = 1.f / (1.f + __expf(-s));
}

// ---------------------------------------------------------------------------
// MFMA flash attention, S^T form. Block = (b,h,64-q tile). r13: no-max
// softmax (scores bounded: RMS-normed q,k, scale 0.1 -> |S|<=6.4, exp<=600,
// sum<=1.2e6, f32-safe) -- removes fmax chain + 2 shuffle reduces + alpha
// rescale. T5 setprio around MFMA clusters (independent blocks, 4/CU).
// ---------------------------------------------------------------------------
__global__ __launch_bounds__(256) void attn3(
    const u16* __restrict__ q, const u16* __restrict__ k, const u16* __restrict__ vt,
    const float* __restrict__ gate, u16* __restrict__ y) {
  __shared__ __attribute__((aligned(16))) unsigned char smem[16384];
  const int tid = threadIdx.x;
  const int wv = tid >> 6, lane = tid & 63, lo = lane & 15, hi = lane >> 4;
  const int idx = blockIdx.x;
  const int qt = 31 - (idx >> 5);
  const int bh = idx & 31;
  const int b = bh >> 4, h = bh & 15;
  const int qb = qt << 6;

  const int qrow = b * T_ + qb + wv * 16 + lo;
  const u16* qp = q + (size_t)qrow * DIM_ + h * HD_;
  const bf16x8 qf0 = *(const bf16x8*)(qp + hi * 8);
  const bf16x8 qf1 = *(const bf16x8*)(qp + 32 + hi * 8);

  f32x4 o[4];
#pragma unroll
  for (int i = 0; i < 4; ++i) o[i] = (f32x4){0.f, 0.f, 0.f, 0.f};
  float lrun = 0.f;    // sum of exp(S); no running max needed (S bounded)

  const int sl = tid & 63, skh = (tid >> 6) & 1, st0 = tid >> 7;
  const int srow = sl & 15, skk = skh * 32 + ((sl >> 4) << 3);
  const u16* kg0 = k + ((size_t)(b * T_ + st0 * 16 + srow)) * DIM_ + h * HD_ + skk;
  const u16* kg1 = kg0 + (size_t)32 * DIM_;
  const u16* vg0 = vt + ((size_t)(bh * HD_ + st0 * 16 + srow)) * T_ + skk;
  const u16* vg1 = vg0 + (size_t)32 * T_;

  uint4 kr0 = *(const uint4*)kg0, kr1 = *(const uint4*)kg1;
  uint4 vr0 = *(const uint4*)vg0, vr1 = *(const uint4*)vg1;

  const int off0 = tid << 4, off1 = (tid + 256) << 4;

  for (int tix = 0; tix <= qt; ++tix) {
    __syncthreads();
    *(uint4*)(smem + off0) = kr0;
    *(uint4*)(smem + off1) = kr1;
    *(uint4*)(smem + 8192 + off0) = vr0;
    *(uint4*)(smem + 8192 + off1) = vr1;
    if (tix < qt) {
      const size_t ko = (size_t)(tix + 1) * 64 * DIM_;
      const size_t vo = (size_t)(tix + 1) * 64;
      kr0 = *(const uint4*)(kg0 + ko); kr1 = *(const uint4*)(kg1 + ko);
      vr0 = *(const uint4*)(vg0 + vo); vr1 = *(const uint4*)(vg1 + vo);
    }
    __syncthreads();

    f32x4 stl[4];
#pragma unroll
    for (int kt = 0; kt < 4; ++kt) stl[kt] = (f32x4){0.f, 0.f, 0.f, 0.f};
    __builtin_amdgcn_s_setprio(1);
#pragma unroll
    for (int kh = 0; kh < 2; ++kh) {
      const bf16x8 qb_ = kh ? qf1 : qf0;
#pragma unroll
      for (int kt = 0; kt < 4; ++kt) {
        const bf16x8 af = *(const bf16x8*)(smem + (((kt * 2 + kh) * 64 + lane) << 4));
        stl[kt] = MFMA16(af, qb_, stl[kt]);
      }
    }
    __builtin_amdgcn_s_setprio(0);
    const bool diag = (tix == qt);
    // no-max softmax: P = exp(S), accumulate row sum only.
    float ps = 0.f;
#pragma unroll
    for (int kt = 0; kt < 4; ++kt)
#pragma unroll
      for (int r = 0; r < 4; ++r) {
        float s = stl[kt][r] * SCALE_;
        if (diag && (kt * 16 + hi * 4 + r > wv * 16 + lo)) s = -3e38f;
        const float e = __expf(s);
        stl[kt][r] = e;
        ps += e;
      }
    ps += __shfl_xor(ps, 16, 64);
    ps += __shfl_xor(ps, 32, 64);
    lrun += ps;

    u32 pkv[4][2];
#pragma unroll
    for (int kt = 0; kt < 4; ++kt) {
      pkv[kt][0] = pk2(stl[kt][0], stl[kt][1]);
      pkv[kt][1] = pk2(stl[kt][2], stl[kt][3]);
    }
#pragma unroll
    for (int kh = 0; kh < 2; ++kh) {
      uint4 w4;
      u32* w4p = (u32*)&w4;
#pragma unroll
      for (int wd = 0; wd < 4; ++wd) {
        const int src = (2 * (hi & 1) + (wd >> 1)) * 16 + lo;
        const u32 a  = (u32)__shfl((int)pkv[2 * kh][wd & 1], src, 64);
        const u32 bb = (u32)__shfl((int)pkv[2 * kh + 1][wd & 1], src, 64);
        w4p[wd] = (hi < 2) ? a : bb;
      }
      const bf16x8 pf = __builtin_bit_cast(bf16x8, w4);
      __builtin_amdgcn_s_setprio(1);
#pragma unroll
      for (int dt = 0; dt < 4; ++dt) {
        const bf16x8 vf = *(const bf16x8*)(smem + 8192 + (((dt * 2 + kh) * 64 + lane) << 4));
        o[dt] = MFMA16(vf, pf, o[dt]);
      }
      __builtin_amdgcn_s_setprio(0);
    }
  }

  const float inv = gate[(size_t)qrow * H_ + h] / lrun;
  u16* yrow = y + (size_t)qrow * DIM_ + h * HD_;
#pragma unroll
  for (int dt = 0; dt < 4; ++dt) {
    ushort4 pq;
    pq.x = f2b(o[dt][0] * inv); pq.y = f2b(o[dt][1] * inv);
    pq.z = f2b(o[dt][2] * inv); pq.w = f2b(o[dt][3] * inv);
    *(ushort4*)(yrow + dt * 16 + hi * 4) = pq;
  }
}

// ---------------------------------------------------------------------------
extern "C" void kernel_launch(void* const* d_in, const int* in_sizes, int n_in,
                              void* d_out, int out_size, void* d_ws, size_t ws_size,
                              hipStream_t stream) {
  const float* x    = (const float*)d_in[0];
  const float* v1   = (const float*)d_in[1];
  const float* Wq   = (const float*)d_in[2];
  const float* Wk   = (const float*)d_in[3];
  const float* Wv   = (const float*)d_in[4];
  const float* Wp   = (const float*)d_in[5];
  const float* Wg   = (const float*)d_in[6];
  const float* lamb = (const float*)d_in[7];

  const size_t NX = (size_t)NROW * DIM_;        // 4M
  const size_t NW = (size_t)DIM_ * DIM_;        // 1M

  u16* q  = (u16*)d_ws;                         // also y (in-place)
  u16* k  = q + NX;
  u16* vt = k + NX;                             // [bh][d][t]
  u16* xb = vt + NX;
  u16* wb = xb + NX;                            // wqb|wkb|wvb|wpb (4M)
  float* gate = (float*)(wb + 4 * NW);          // total ws: 40.25 MB

  const dim3 bb(256);

  convert_all<<<dim3(8192), bb, 0, stream>>>(x, Wq, Wk, Wv, Wp, xb, wb);
  gemm_rp<false><<<dim3(NROW / 128, 24), bb, 0, stream>>>(
      xb, wb, q, k, vt, nullptr, v1, lamb);
  gate_kernel<<<dim3(NROW * H_ / 256), bb, 0, stream>>>(x, Wg, gate);
  attn3<<<dim3(B_ * H_ * (T_ / 64)), bb, 0, stream>>>(q, k, vt, gate, q);
  gemm_rp<true><<<dim3(NROW / 128, 8), bb, 0, stream>>>(
      q, wb + 3 * NW, nullptr, nullptr, nullptr, (float*)d_out, nullptr, nullptr);
}

// Round 4
// 221.020 us; speedup vs baseline: 1.0801x; 1.0015x over previous
//
#include <hip/hip_runtime.h>
#include <math.h>

// ---------------------------------------------------------------------------
// CausalSelfAttention fused pipeline, MI355X gfx950.  Round 14.
// r13 post-mortem: QKV stages 384 MB in 67us = 5.7 TB/s from L2/L3 (FETCH
// only 40MB) -> cache-fabric-BW bound. Dispatch round-robins sharing blocks
// across XCDs so panel re-reads go to L3. r14:
//  (a) T1 bijective XCD swizzle, m-chunked, for both GEMMs: XCD x owns
//      m in {4x..4x+3} x all by -> per-XCD hot set = 4 A-panels (1MB,
//      L2-resident) + ~3 B-panels (768KB). Staging becomes L2-served.
//  (b) attn3: bh-chunked swizzle (XCD x owns bh {4x..4x+3}; K/V 2MB
//      L2-resident) + port of the r12 pipeline: 3x16KB LDS ring,
//      global_load_lds staging, counted vmcnt(4), ONE barrier per K/V tile
//      (was: reg round-trip + 2 drain barriers).
// GEMM K-loop structure unchanged from r12 (ring + counted vmcnt).
// Workspace: q(=y) 8MB | k 8MB | vt 8MB | xb 8MB | w[4]b 8MB | gate 256KB.
// ---------------------------------------------------------------------------

#define B_    2
#define T_    2048
#define DIM_  1024
#define H_    16
#define HD_   64
#define NROW  (B_ * T_)
#define EPS_  1.1920929e-07f
#define SCALE_ 0.1f
#define LOG2_10K 13.287712379549449f
#define INV2PI 0.15915494309189535f

typedef unsigned short u16;
typedef unsigned int   u32;
typedef __bf16 bf16x8 __attribute__((ext_vector_type(8)));
typedef __bf16 bf16x2 __attribute__((ext_vector_type(2)));
typedef float  f32x4  __attribute__((ext_vector_type(4)));

__device__ __forceinline__ u16 f2b(float f) {
  u32 u = __float_as_uint(f);
  u += 0x7fffu + ((u >> 16) & 1u);       // RNE
  return (u16)(u >> 16);
}
__device__ __forceinline__ u32 pk2(float a, float b) {
#if __has_builtin(__builtin_amdgcn_cvt_pk_bf16_f32)
  bf16x2 r = __builtin_amdgcn_cvt_pk_bf16_f32(a, b);
  return __builtin_bit_cast(u32, r);
#else
  return (u32)f2b(a) | ((u32)f2b(b) << 16);
#endif
}
// fast sin/cos of (rev revolutions): fract to [0,1), then v_sin/v_cos
__device__ __forceinline__ void fast_sincos_rev(float rev, float* s, float* c) {
  const float r = rev - floorf(rev);
#if __has_builtin(__builtin_amdgcn_sinf) && __has_builtin(__builtin_amdgcn_cosf)
  *s = __builtin_amdgcn_sinf(r);
  *c = __builtin_amdgcn_cosf(r);
#else
  *s = __sinf(r * 6.283185307179586f);
  *c = __cosf(r * 6.283185307179586f);
#endif
}
#define MFMA16(a,b,c) __builtin_amdgcn_mfma_f32_16x16x32_bf16((a),(b),(c),0,0,0)

// async global -> LDS, 16B per lane. LDS dest must be wave-uniform base;
// HW writes lane i at base + i*16. Global src is per-lane.
typedef const __attribute__((address_space(1))) unsigned char gbuf_t;
typedef __attribute__((address_space(3))) unsigned char lbuf_t;
__device__ __forceinline__ void gload_lds16(const u16* g, unsigned char* l) {
  __builtin_amdgcn_global_load_lds((gbuf_t*)g, (lbuf_t*)l, 16, 0, 0);
}

// ---------------------------------------------------------------------------
// Convert pass: x (4M) and Wq/Wk/Wv/Wp (1M each) f32 -> bf16.
// ---------------------------------------------------------------------------
__global__ __launch_bounds__(256) void convert_all(
    const float* __restrict__ x, const float* __restrict__ Wq,
    const float* __restrict__ Wk, const float* __restrict__ Wv,
    const float* __restrict__ Wp,
    u16* __restrict__ xb, u16* __restrict__ wb /* wqb|wkb|wvb|wpb */) {
  const int i = blockIdx.x * 256 + threadIdx.x;       // 0 .. 2M-1 groups
  const float* src;
  u16* dst;
  int off;
  if (i < 1048576)       { src = x;  dst = xb;            off = i; }
  else if (i < 1310720)  { src = Wq; dst = wb;            off = i - 1048576; }
  else if (i < 1572864)  { src = Wk; dst = wb + 1048576;  off = i - 1310720; }
  else if (i < 1835008)  { src = Wv; dst = wb + 2097152;  off = i - 1572864; }
  else                   { src = Wp; dst = wb + 3145728;  off = i - 1835008; }
  const float4 f = ((const float4*)src)[off];
  uint2 o;
  o.x = pk2(f.x, f.y);
  o.y = pk2(f.z, f.w);
  ((uint2*)dst)[off] = o;
}

// ---------------------------------------------------------------------------
// Deep-prefetch GEMM: C[row,n] = sum_k A[row,k]*W[n,k].
// 128x128 block tile, BK=32, 4 waves x (64x64 via 4x4 16x16x32 accs).
// LDS 48KB: 3 x (A 8KB | B 8KB) ring. K-loop per step c:
//   sched_barrier / s_waitcnt vmcnt(4) / s_barrier / issue L(c+2) /
//   8 ds_read_b128 + 16 MFMA from buf c%3.
// 1-D grid with bijective m-chunk XCD swizzle: xcd = raw&7 owns
// m-blocks {4*xcd .. 4*xcd+3} for all by -> A panels L2-resident.
// IS_PROJ=false: grid 768, by=jj>>2 in 0..23, mode=by>>3.
// IS_PROJ=true:  grid 256, by=jj>>2 in 0..7, f32 out.
// ---------------------------------------------------------------------------
template <bool IS_PROJ>
__global__ __launch_bounds__(256) void gemm_rp(
    const u16* __restrict__ Ab, const u16* __restrict__ Wb,
    u16* __restrict__ qo, u16* __restrict__ ko, u16* __restrict__ vto,
    float* __restrict__ fo, const float* __restrict__ v1,
    const float* __restrict__ lambp) {
  __shared__ __attribute__((aligned(16))) unsigned char sm[49152];
  const int tid  = threadIdx.x;
  const int w    = tid >> 6;
  const int lane = tid & 63;
  const int lo = lane & 15, hi = lane >> 4;
  // XCD-aware decode (assumes HW round-robin: block raw -> XCD raw%8)
  const int raw = blockIdx.x;
  const int xcd = raw & 7;
  const int jj  = raw >> 3;
  const int m0 = (xcd * 4 + (jj & 3)) << 7;     // m-chunk per XCD
  const int by = jj >> 2;
  const int mode = IS_PROJ ? 3 : (by >> 3);
  const int n0 = IS_PROJ ? (by << 7) : ((by & 7) << 7);
  const u16* W = IS_PROJ ? Wb : (Wb + (size_t)mode * (DIM_ * DIM_));

  const int wm = w & 1, wn = w >> 1;

  // per-lane global srcs in fragment order (row = blk*16+lo, kchunk = hi*8)
  const u16* agA0 = Ab + (size_t)(m0 + (2 * w + 0) * 16 + lo) * DIM_ + (hi << 3);
  const u16* agA1 = Ab + (size_t)(m0 + (2 * w + 1) * 16 + lo) * DIM_ + (hi << 3);
  const u16* agB0 = W  + (size_t)(n0 + (2 * w + 0) * 16 + lo) * DIM_ + (hi << 3);
  const u16* agB1 = W  + (size_t)(n0 + (2 * w + 1) * 16 + lo) * DIM_ + (hi << 3);

  f32x4 acc[4][4];
#pragma unroll
  for (int i = 0; i < 4; ++i)
#pragma unroll
    for (int j = 0; j < 4; ++j) acc[i][j] = (f32x4){0.f, 0.f, 0.f, 0.f};

  // prologue: stage K-tiles 0 and 1 into bufs 0 and 1 (8 loads in flight)
  {
    unsigned char* ad0 = sm + (2 * w) * 1024;
    gload_lds16(agA0, ad0);
    gload_lds16(agA1, ad0 + 1024);
    gload_lds16(agB0, ad0 + 8192);
    gload_lds16(agB1, ad0 + 9216);
    agA0 += 32; agA1 += 32; agB0 += 32; agB1 += 32;
    unsigned char* ad1 = sm + 16384 + (2 * w) * 1024;
    gload_lds16(agA0, ad1);
    gload_lds16(agA1, ad1 + 1024);
    gload_lds16(agB0, ad1 + 8192);
    gload_lds16(agB1, ad1 + 9216);
    agA0 += 32; agA1 += 32; agB0 += 32; agB1 += 32;
  }

  int cr = 0;   // read buffer  (= c % 3)
  int cw = 2;   // write buffer (= (c+2) % 3)
  for (int kc = 0; kc < DIM_; kc += 32) {
    __builtin_amdgcn_sched_barrier(0);
    if (kc + 32 < DIM_) {
      asm volatile("s_waitcnt vmcnt(4)" ::: "memory");  // L(c) landed
    } else {
      asm volatile("s_waitcnt vmcnt(0)" ::: "memory");  // last tile
    }
    __builtin_amdgcn_s_barrier();
    __builtin_amdgcn_sched_barrier(0);
    if (kc + 64 < DIM_) {
      // issue L(c+2) into ring buffer cw (last read at step c-1, barrier-safe)
      unsigned char* ad = sm + cw * 16384 + (2 * w) * 1024;
      gload_lds16(agA0, ad);
      gload_lds16(agA1, ad + 1024);
      gload_lds16(agB0, ad + 8192);
      gload_lds16(agB1, ad + 9216);
      agA0 += 32; agA1 += 32; agB0 += 32; agB1 += 32;
    }
    const unsigned char* Acur = sm + cr * 16384;
    const unsigned char* Bcur = Acur + 8192;
    bf16x8 bfr[4];
#pragma unroll
    for (int nt = 0; nt < 4; ++nt)
      bfr[nt] = *(const bf16x8*)(Bcur + (((wn * 4 + nt) * 64 + lane) << 4));
#pragma unroll
    for (int mt = 0; mt < 4; ++mt) {
      const bf16x8 af = *(const bf16x8*)(Acur + (((wm * 4 + mt) * 64 + lane) << 4));
#pragma unroll
      for (int nt = 0; nt < 4; ++nt)
        acc[mt][nt] = MFMA16(af, bfr[nt], acc[mt][nt]);
    }
    cr = (cr == 2) ? 0 : cr + 1;
    cw = (cw == 2) ? 0 : cw + 1;
  }

  // ---- register epilogues ----
  const int head = (n0 >> 6) + wn;
  if (mode <= 1) {
    u16* C = (mode == 0) ? qo : ko;
    // frequencies in REVOLUTIONS (1/2pi folded in)
    const float if0 = exp2f(-(float)lo * (LOG2_10K / 32.f)) * INV2PI;
    const float if1 = exp2f(-(float)(lo + 16) * (LOG2_10K / 32.f)) * INV2PI;
#pragma unroll
    for (int mt = 0; mt < 4; ++mt)
#pragma unroll
      for (int r = 0; r < 4; ++r) {
        float ss = 0.f;
#pragma unroll
        for (int nt = 0; nt < 4; ++nt) { const float v = acc[mt][nt][r]; ss += v * v; }
        ss += __shfl_xor(ss, 1, 64); ss += __shfl_xor(ss, 2, 64);
        ss += __shfl_xor(ss, 4, 64); ss += __shfl_xor(ss, 8, 64);
        const float scl = rsqrtf(ss * (1.f / 64.f) + EPS_);
        const int row_g = m0 + wm * 64 + mt * 16 + hi * 4 + r;
        const float tpos = (float)(row_g & (T_ - 1));
        float sn0, cs0, sn1, cs1;
        fast_sincos_rev(tpos * if0, &sn0, &cs0);
        fast_sincos_rev(tpos * if1, &sn1, &cs1);
        u16* crow = C + (size_t)row_g * DIM_ + head * HD_;
        const float x10 = acc[mt][0][r] * scl, x11 = acc[mt][1][r] * scl;
        const float x20 = acc[mt][2][r] * scl, x21 = acc[mt][3][r] * scl;
        crow[lo]      = f2b(x10 * cs0 + x20 * sn0);
        crow[16 + lo] = f2b(x11 * cs1 + x21 * sn1);
        crow[32 + lo] = f2b(x20 * cs0 - x10 * sn0);
        crow[48 + lo] = f2b(x21 * cs1 - x11 * sn1);
      }
  } else if (mode == 2) {
    const float lam = lambp[0];
#pragma unroll
    for (int mt = 0; mt < 4; ++mt)
#pragma unroll
      for (int r = 0; r < 4; ++r) {
        const int row_g = m0 + wm * 64 + mt * 16 + hi * 4 + r;
        const int bb = row_g >> 11, tt = row_g & (T_ - 1);
        const int bh = bb * H_ + head;
        const float* v1r = v1 + (size_t)row_g * DIM_ + head * HD_;
#pragma unroll
        for (int nt = 0; nt < 4; ++nt) {
          const int d = nt * 16 + lo;
          const float ov = (1.f - lam) * acc[mt][nt][r] + lam * v1r[d];
          vto[((size_t)(bh * HD_ + d)) * T_ + tt] = f2b(ov);   // transposed
        }
      }
  } else {
#pragma unroll
    for (int mt = 0; mt < 4; ++mt)
#pragma unroll
      for (int r = 0; r < 4; ++r) {
        const int row_g = m0 + wm * 64 + mt * 16 + hi * 4 + r;
        float* orow = fo + (size_t)row_g * DIM_ + n0 + wn * 64;
#pragma unroll
        for (int nt = 0; nt < 4; ++nt) orow[nt * 16 + lo] = acc[mt][nt][r];
      }
  }
}

// ---------------------------------------------------------------------------
// gate[n,h] = sigmoid( sum_{j<12} x[n,j]*Wg[h,j] )
// ---------------------------------------------------------------------------
__global__ __launch_bounds__(256) void gate_kernel(
    const float* __restrict__ x, const float* __restrict__ Wg,
    float* __restrict__ gate) {
  const int id = blockIdx.x * 256 + threadIdx.x;
  const int n = id >> 4, h = id & 15;
  const float* xr = x + (size_t)n * DIM_;
  const float* wr = Wg + h * 12;
  float s = 0.f;
#pragma unroll
  for (int j = 0; j < 12; ++j) s += xr[j] * wr[j];
  gate[id] = 1.f / (1.f + __expf(-s));
}

// ---------------------------------------------------------------------------
// MFMA flash attention, S^T form, no-max softmax (r13-verified bound).
// r14: bh-chunked XCD swizzle (XCD x owns bh {4x..4x+3}: K/V 2MB/XCD,
// L2-resident) + r12-style pipeline: 3x16KB LDS ring, global_load_lds
// staging, counted vmcnt(4), ONE barrier per K/V tile.
// Ring hazard: iter t writes slot (t+2)%3=(t-1)%3; its iter t-1 ds_reads
// are MFMA-consumed (auto lgkmcnt) before any wave reaches barrier t.
// ---------------------------------------------------------------------------
__global__ __launch_bounds__(256) void attn3(
    const u16* __restrict__ q, const u16* __restrict__ k, const u16* __restrict__ vt,
    const float* __restrict__ gate, u16* __restrict__ y) {
  __shared__ __attribute__((aligned(16))) unsigned char smem[49152];
  const int tid = threadIdx.x;
  const int wv = tid >> 6, lane = tid & 63, lo = lane & 15, hi = lane >> 4;
  // XCD decode: xcd owns 4 bh values; qt descending within XCD for balance.
  const int raw = blockIdx.x;                  // 0..1023
  const int xcd = raw & 7;
  const int jj  = raw >> 3;                    // 0..127
  const int qt = 31 - (jj >> 2);               // 31..0
  const int bh = xcd * 4 + (jj & 3);           // 0..31
  const int b = bh >> 4, h = bh & 15;
  const int qb = qt << 6;

  const int qrow = b * T_ + qb + wv * 16 + lo;
  const u16* qp = q + (size_t)qrow * DIM_ + h * HD_;
  const bf16x8 qf0 = *(const bf16x8*)(qp + hi * 8);
  const bf16x8 qf1 = *(const bf16x8*)(qp + 32 + hi * 8);

  f32x4 o[4];
#pragma unroll
  for (int i = 0; i < 4; ++i) o[i] = (f32x4){0.f, 0.f, 0.f, 0.f};
  float lrun = 0.f;    // sum of exp(S); no running max needed (S bounded)

  const int sl = tid & 63, skh = (tid >> 6) & 1, st0 = tid >> 7;
  const int srow = sl & 15, skk = skh * 32 + ((sl >> 4) << 3);
  const u16* kg0 = k + ((size_t)(b * T_ + st0 * 16 + srow)) * DIM_ + h * HD_ + skk;
  const u16* kg1 = kg0 + (size_t)32 * DIM_;
  const u16* vg0 = vt + ((size_t)(bh * HD_ + st0 * 16 + srow)) * T_ + skk;
  const u16* vg1 = vg0 + (size_t)32 * T_;
  const int wub = (tid >> 6) << 10;            // wave-uniform LDS sub-base

  // prologue: stage tiles 0 and 1 (clamped) into slots 0,1
  {
    gload_lds16(kg0, smem + wub);
    gload_lds16(kg1, smem + 4096 + wub);
    gload_lds16(vg0, smem + 8192 + wub);
    gload_lds16(vg1, smem + 12288 + wub);
    const int t1 = (qt >= 1) ? 1 : 0;
    const size_t ko = (size_t)t1 * 64 * DIM_;
    const size_t vo = (size_t)t1 * 64;
    unsigned char* b1 = smem + 16384;
    gload_lds16(kg0 + ko, b1 + wub);
    gload_lds16(kg1 + ko, b1 + 4096 + wub);
    gload_lds16(vg0 + vo, b1 + 8192 + wub);
    gload_lds16(vg1 + vo, b1 + 12288 + wub);
  }

  int sr = 0, sw = 2;
  for (int tix = 0; tix <= qt; ++tix) {
    __builtin_amdgcn_sched_barrier(0);
    if (tix < qt) {
      asm volatile("s_waitcnt vmcnt(4)" ::: "memory");  // tile tix landed
    } else {
      asm volatile("s_waitcnt vmcnt(0)" ::: "memory");
    }
    __builtin_amdgcn_s_barrier();
    __builtin_amdgcn_sched_barrier(0);
    if (tix + 2 <= qt) {
      const size_t ko = (size_t)(tix + 2) * 64 * DIM_;
      const size_t vo = (size_t)(tix + 2) * 64;
      unsigned char* base = smem + sw * 16384;
      gload_lds16(kg0 + ko, base + wub);
      gload_lds16(kg1 + ko, base + 4096 + wub);
      gload_lds16(vg0 + vo, base + 8192 + wub);
      gload_lds16(vg1 + vo, base + 12288 + wub);
    }
    const unsigned char* kb = smem + sr * 16384;
    const unsigned char* vb = kb + 8192;

    f32x4 stl[4];
#pragma unroll
    for (int kt = 0; kt < 4; ++kt) stl[kt] = (f32x4){0.f, 0.f, 0.f, 0.f};
    __builtin_amdgcn_s_setprio(1);
#pragma unroll
    for (int kh = 0; kh < 2; ++kh) {
      const bf16x8 qb_ = kh ? qf1 : qf0;
#pragma unroll
      for (int kt = 0; kt < 4; ++kt) {
        const bf16x8 af = *(const bf16x8*)(kb + (((kt * 2 + kh) * 64 + lane) << 4));
        stl[kt] = MFMA16(af, qb_, stl[kt]);
      }
    }
    __builtin_amdgcn_s_setprio(0);
    const bool diag = (tix == qt);
    // no-max softmax: P = exp(S), accumulate row sum only.
    float ps = 0.f;
#pragma unroll
    for (int kt = 0; kt < 4; ++kt)
#pragma unroll
      for (int r = 0; r < 4; ++r) {
        float s = stl[kt][r] * SCALE_;
        if (diag && (kt * 16 + hi * 4 + r > wv * 16 + lo)) s = -3e38f;
        const float e = __expf(s);
        stl[kt][r] = e;
        ps += e;
      }
    ps += __shfl_xor(ps, 16, 64);
    ps += __shfl_xor(ps, 32, 64);
    lrun += ps;

    u32 pkv[4][2];
#pragma unroll
    for (int kt = 0; kt < 4; ++kt) {
      pkv[kt][0] = pk2(stl[kt][0], stl[kt][1]);
      pkv[kt][1] = pk2(stl[kt][2], stl[kt][3]);
    }
#pragma unroll
    for (int kh = 0; kh < 2; ++kh) {
      uint4 w4;
      u32* w4p = (u32*)&w4;
#pragma unroll
      for (int wd = 0; wd < 4; ++wd) {
        const int src = (2 * (hi & 1) + (wd >> 1)) * 16 + lo;
        const u32 a  = (u32)__shfl((int)pkv[2 * kh][wd & 1], src, 64);
        const u32 bb = (u32)__shfl((int)pkv[2 * kh + 1][wd & 1], src, 64);
        w4p[wd] = (hi < 2) ? a : bb;
      }
      const bf16x8 pf = __builtin_bit_cast(bf16x8, w4);
      __builtin_amdgcn_s_setprio(1);
#pragma unroll
      for (int dt = 0; dt < 4; ++dt) {
        const bf16x8 vf = *(const bf16x8*)(vb + (((dt * 2 + kh) * 64 + lane) << 4));
        o[dt] = MFMA16(vf, pf, o[dt]);
      }
      __builtin_amdgcn_s_setprio(0);
    }
    sr = (sr == 2) ? 0 : sr + 1;
    sw = (sw == 2) ? 0 : sw + 1;
  }

  const float inv = gate[(size_t)qrow * H_ + h] / lrun;
  u16* yrow = y + (size_t)qrow * DIM_ + h * HD_;
#pragma unroll
  for (int dt = 0; dt < 4; ++dt) {
    ushort4 pq;
    pq.x = f2b(o[dt][0] * inv); pq.y = f2b(o[dt][1] * inv);
    pq.z = f2b(o[dt][2] * inv); pq.w = f2b(o[dt][3] * inv);
    *(ushort4*)(yrow + dt * 16 + hi * 4) = pq;
  }
}

// ---------------------------------------------------------------------------
extern "C" void kernel_launch(void* const* d_in, const int* in_sizes, int n_in,
                              void* d_out, int out_size, void* d_ws, size_t ws_size,
                              hipStream_t stream) {
  const float* x    = (const float*)d_in[0];
  const float* v1   = (const float*)d_in[1];
  const float* Wq   = (const float*)d_in[2];
  const float* Wk   = (const float*)d_in[3];
  const float* Wv   = (const float*)d_in[4];
  const float* Wp   = (const float*)d_in[5];
  const float* Wg   = (const float*)d_in[6];
  const float* lamb = (const float*)d_in[7];

  const size_t NX = (size_t)NROW * DIM_;        // 4M
  const size_t NW = (size_t)DIM_ * DIM_;        // 1M

  u16* q  = (u16*)d_ws;                         // also y (in-place)
  u16* k  = q + NX;
  u16* vt = k + NX;                             // [bh][d][t]
  u16* xb = vt + NX;
  u16* wb = xb + NX;                            // wqb|wkb|wvb|wpb (4M)
  float* gate = (float*)(wb + 4 * NW);          // total ws: 40.25 MB

  const dim3 bb(256);

  convert_all<<<dim3(8192), bb, 0, stream>>>(x, Wq, Wk, Wv, Wp, xb, wb);
  gemm_rp<false><<<dim3(768), bb, 0, stream>>>(
      xb, wb, q, k, vt, nullptr, v1, lamb);
  gate_kernel<<<dim3(NROW * H_ / 256), bb, 0, stream>>>(x, Wg, gate);
  attn3<<<dim3(1024), bb, 0, stream>>>(q, k, vt, gate, q);
  gemm_rp<true><<<dim3(256), bb, 0, stream>>>(
      q, wb + 3 * NW, nullptr, nullptr, nullptr, (float*)d_out, nullptr, nullptr);
}

// Round 5
// 211.213 us; speedup vs baseline: 1.1302x; 1.0464x over previous
//
#include <hip/hip_runtime.h>
#include <math.h>

// ---------------------------------------------------------------------------
// CausalSelfAttention fused pipeline, MI355X gfx950.  Round 15.
// r14 post-mortem: XCD swizzle null, attn ring null. Proper arithmetic:
// QKV GEMM moves 1.18 GB through the LDS port in 68us = 68 B/cyc/CU = the
// SAME pace as m97's 912 TF kernel (80% of the 85 B/cyc ds_read_b128
// ceiling). The kernel is LDS-PORT bound; staging-schedule polish can't
// help. r15: delete LDS from the GEMMs entirely.
//  - convert_all writes xb AND the four W matrices PRE-TILED in MFMA
//    fragment order: chunk(rb,ks) = 16 rows x 32 cols as one contiguous
//    1KB lane-major block. A fragment load is then ONE coalesced
//    global_load_dwordx4 (16B/lane) straight into MFMA operand registers.
//  - gemm_rp: no LDS, no barriers. Ping-pong named reg sets (rule #20),
//    distance-1 prefetch; free-running waves phase-shift so TLP hides
//    latency (impossible under the old lockstep barriers).
//  - attn3 unchanged internally, but its epilogue stores y TILED into the
//    free xb buffer (pure address arithmetic) so proj can consume it as
//    direct-reg A. q/k/vt stay row-major for attn3.
// Workspace: q 8MB | k 8MB | vt 8MB | xb(=y_tiled) 8MB | w[4]b 8MB | gate.
// ---------------------------------------------------------------------------

#define B_    2
#define T_    2048
#define DIM_  1024
#define H_    16
#define HD_   64
#define NROW  (B_ * T_)
#define EPS_  1.1920929e-07f
#define SCALE_ 0.1f
#define LOG2_10K 13.287712379549449f
#define INV2PI 0.15915494309189535f

typedef unsigned short u16;
typedef unsigned int   u32;
typedef __bf16 bf16x8 __attribute__((ext_vector_type(8)));
typedef __bf16 bf16x2 __attribute__((ext_vector_type(2)));
typedef float  f32x4  __attribute__((ext_vector_type(4)));

__device__ __forceinline__ u16 f2b(float f) {
  u32 u = __float_as_uint(f);
  u += 0x7fffu + ((u >> 16) & 1u);       // RNE
  return (u16)(u >> 16);
}
__device__ __forceinline__ u32 pk2(float a, float b) {
#if __has_builtin(__builtin_amdgcn_cvt_pk_bf16_f32)
  bf16x2 r = __builtin_amdgcn_cvt_pk_bf16_f32(a, b);
  return __builtin_bit_cast(u32, r);
#else
  return (u32)f2b(a) | ((u32)f2b(b) << 16);
#endif
}
// fast sin/cos of (rev revolutions): fract to [0,1), then v_sin/v_cos
__device__ __forceinline__ void fast_sincos_rev(float rev, float* s, float* c) {
  const float r = rev - floorf(rev);
#if __has_builtin(__builtin_amdgcn_sinf) && __has_builtin(__builtin_amdgcn_cosf)
  *s = __builtin_amdgcn_sinf(r);
  *c = __builtin_amdgcn_cosf(r);
#else
  *s = __sinf(r * 6.283185307179586f);
  *c = __cosf(r * 6.283185307179586f);
#endif
}
#define MFMA16(a,b,c) __builtin_amdgcn_mfma_f32_16x16x32_bf16((a),(b),(c),0,0,0)

// async global -> LDS (still used by attn3)
typedef const __attribute__((address_space(1))) unsigned char gbuf_t;
typedef __attribute__((address_space(3))) unsigned char lbuf_t;
__device__ __forceinline__ void gload_lds16(const u16* g, unsigned char* l) {
  __builtin_amdgcn_global_load_lds((gbuf_t*)g, (lbuf_t*)l, 16, 0, 0);
}

// ---------------------------------------------------------------------------
// Convert pass -> TILED fragment-major layout.
// TILED(row,col) chunk: rb=row>>4, ks=col>>5; lane=(row&15)+((col>>3)&3)*16;
// elem=col&7. u16 offset = (rb*32+ks)*512 + lane*8 + elem.
// Each thread produces one 16B chunk (8 bf16) = lane-slot of one (rb,ks).
// i < 512K: xb (4M elems). Else: four 1M-elem weights.
// ---------------------------------------------------------------------------
__global__ __launch_bounds__(256) void convert_all(
    const float* __restrict__ x, const float* __restrict__ Wq,
    const float* __restrict__ Wk, const float* __restrict__ Wv,
    const float* __restrict__ Wp,
    u16* __restrict__ xb, u16* __restrict__ wb) {
  const int i = blockIdx.x * 256 + threadIdx.x;       // 0 .. 1M-1 chunks
  const float* src;
  u16* dst;
  int off;
  if (i < 524288) { src = x; dst = xb; off = i; }
  else {
    const int j = i - 524288;
    const int s = j >> 17;                            // 0..3
    off = j & 131071;
    src = (s == 0) ? Wq : (s == 1) ? Wk : (s == 2) ? Wv : Wp;
    dst = wb + (size_t)s * 1048576;
  }
  const int blk = off >> 6, ln = off & 63;
  const int row = ((blk >> 5) << 4) + (ln & 15);
  const int col = ((blk & 31) << 5) + ((ln >> 4) << 3);
  const float4 f0 = *(const float4*)(src + (size_t)row * DIM_ + col);
  const float4 f1 = *(const float4*)(src + (size_t)row * DIM_ + col + 4);
  uint4 o;
  o.x = pk2(f0.x, f0.y); o.y = pk2(f0.z, f0.w);
  o.z = pk2(f1.x, f1.y); o.w = pk2(f1.z, f1.w);
  ((uint4*)dst)[off] = o;
}

// ---------------------------------------------------------------------------
// Direct-to-register GEMM, NO LDS, NO barriers.
// 128x128 block tile, 4 waves x 64x64 (4x4 16x16x32 accs). A,B pre-tiled:
// frag load = 1 coalesced global_load_dwordx4 per inst. Ping-pong reg sets
// (E/O), distance-1 prefetch; free-running waves hide latency via TLP.
// IS_PROJ=false: grid 768 (XCD m-chunk decode), mode=by>>3: 0 q(rope)
//   1 k(rope) 2 v(blend, transposed store). IS_PROJ=true: grid 256, f32 out.
// ---------------------------------------------------------------------------
template <bool IS_PROJ>
__global__ __launch_bounds__(256) void gemm_rp(
    const u16* __restrict__ Ab, const u16* __restrict__ Wb,
    u16* __restrict__ qo, u16* __restrict__ ko, u16* __restrict__ vto,
    float* __restrict__ fo, const float* __restrict__ v1,
    const float* __restrict__ lambp) {
  const int tid  = threadIdx.x;
  const int w    = tid >> 6;
  const int lane = tid & 63;
  const int lo = lane & 15, hi = lane >> 4;
  const int raw = blockIdx.x;
  const int xcd = raw & 7;
  const int jj  = raw >> 3;
  const int m0 = (xcd * 4 + (jj & 3)) << 7;
  const int by = jj >> 2;
  const int mode = IS_PROJ ? 3 : (by >> 3);
  const int n0 = IS_PROJ ? (by << 7) : ((by & 7) << 7);
  const u16* W = IS_PROJ ? Wb : (Wb + (size_t)mode * (DIM_ * DIM_));
  const int wm = w & 1, wn = w >> 1;

  // tiled bases: rb stride = 32 chunks * 512 u16 = 16384 u16
  const u16* pA = Ab + (size_t)((m0 >> 4) + wm * 4) * 16384 + lane * 8;
  const u16* pB = W  + (size_t)((n0 >> 4) + wn * 4) * 16384 + lane * 8;

  f32x4 acc[4][4];
#pragma unroll
  for (int i = 0; i < 4; ++i)
#pragma unroll
    for (int j = 0; j < 4; ++j) acc[i][j] = (f32x4){0.f, 0.f, 0.f, 0.f};

  bf16x8 aE[4], bE[4], aO[4], bO[4];
#pragma unroll
  for (int t = 0; t < 4; ++t) {
    aE[t] = *(const bf16x8*)(pA + t * 16384);
    bE[t] = *(const bf16x8*)(pB + t * 16384);
  }
  for (int ks = 0; ks < 32; ks += 2) {
#pragma unroll
    for (int t = 0; t < 4; ++t) {
      aO[t] = *(const bf16x8*)(pA + t * 16384 + (ks + 1) * 512);
      bO[t] = *(const bf16x8*)(pB + t * 16384 + (ks + 1) * 512);
    }
#pragma unroll
    for (int mt = 0; mt < 4; ++mt)
#pragma unroll
      for (int nt = 0; nt < 4; ++nt)
        acc[mt][nt] = MFMA16(aE[mt], bE[nt], acc[mt][nt]);
    const int kn = (ks + 2 < 32) ? (ks + 2) : 0;   // clamped dummy on last
#pragma unroll
    for (int t = 0; t < 4; ++t) {
      aE[t] = *(const bf16x8*)(pA + t * 16384 + kn * 512);
      bE[t] = *(const bf16x8*)(pB + t * 16384 + kn * 512);
    }
#pragma unroll
    for (int mt = 0; mt < 4; ++mt)
#pragma unroll
      for (int nt = 0; nt < 4; ++nt)
        acc[mt][nt] = MFMA16(aO[mt], bO[nt], acc[mt][nt]);
  }

  // ---- register epilogues (unchanged) ----
  const int head = (n0 >> 6) + wn;
  if (mode <= 1) {
    u16* C = (mode == 0) ? qo : ko;
    const float if0 = exp2f(-(float)lo * (LOG2_10K / 32.f)) * INV2PI;
    const float if1 = exp2f(-(float)(lo + 16) * (LOG2_10K / 32.f)) * INV2PI;
#pragma unroll
    for (int mt = 0; mt < 4; ++mt)
#pragma unroll
      for (int r = 0; r < 4; ++r) {
        float ss = 0.f;
#pragma unroll
        for (int nt = 0; nt < 4; ++nt) { const float v = acc[mt][nt][r]; ss += v * v; }
        ss += __shfl_xor(ss, 1, 64); ss += __shfl_xor(ss, 2, 64);
        ss += __shfl_xor(ss, 4, 64); ss += __shfl_xor(ss, 8, 64);
        const float scl = rsqrtf(ss * (1.f / 64.f) + EPS_);
        const int row_g = m0 + wm * 64 + mt * 16 + hi * 4 + r;
        const float tpos = (float)(row_g & (T_ - 1));
        float sn0, cs0, sn1, cs1;
        fast_sincos_rev(tpos * if0, &sn0, &cs0);
        fast_sincos_rev(tpos * if1, &sn1, &cs1);
        u16* crow = C + (size_t)row_g * DIM_ + head * HD_;
        const float x10 = acc[mt][0][r] * scl, x11 = acc[mt][1][r] * scl;
        const float x20 = acc[mt][2][r] * scl, x21 = acc[mt][3][r] * scl;
        crow[lo]      = f2b(x10 * cs0 + x20 * sn0);
        crow[16 + lo] = f2b(x11 * cs1 + x21 * sn1);
        crow[32 + lo] = f2b(x20 * cs0 - x10 * sn0);
        crow[48 + lo] = f2b(x21 * cs1 - x11 * sn1);
      }
  } else if (mode == 2) {
    const float lam = lambp[0];
#pragma unroll
    for (int mt = 0; mt < 4; ++mt)
#pragma unroll
      for (int r = 0; r < 4; ++r) {
        const int row_g = m0 + wm * 64 + mt * 16 + hi * 4 + r;
        const int bb = row_g >> 11, tt = row_g & (T_ - 1);
        const int bh = bb * H_ + head;
        const float* v1r = v1 + (size_t)row_g * DIM_ + head * HD_;
#pragma unroll
        for (int nt = 0; nt < 4; ++nt) {
          const int d = nt * 16 + lo;
          const float ov = (1.f - lam) * acc[mt][nt][r] + lam * v1r[d];
          vto[((size_t)(bh * HD_ + d)) * T_ + tt] = f2b(ov);   // transposed
        }
      }
  } else {
#pragma unroll
    for (int mt = 0; mt < 4; ++mt)
#pragma unroll
      for (int r = 0; r < 4; ++r) {
        const int row_g = m0 + wm * 64 + mt * 16 + hi * 4 + r;
        float* orow = fo + (size_t)row_g * DIM_ + n0 + wn * 64;
#pragma unroll
        for (int nt = 0; nt < 4; ++nt) orow[nt * 16 + lo] = acc[mt][nt][r];
      }
  }
}

// ---------------------------------------------------------------------------
// gate[n,h] = sigmoid( sum_{j<12} x[n,j]*Wg[h,j] )
// ---------------------------------------------------------------------------
__global__ __launch_bounds__(256) void gate_kernel(
    const float* __restrict__ x, const float* __restrict__ Wg,
    float* __restrict__ gate) {
  const int id = blockIdx.x * 256 + threadIdx.x;
  const int n = id >> 4, h = id & 15;
  const float* xr = x + (size_t)n * DIM_;
  const float* wr = Wg + h * 12;
  float s = 0.f;
#pragma unroll
  for (int j = 0; j < 12; ++j) s += xr[j] * wr[j];
  gate[id] = 1.f / (1.f + __expf(-s));
}

// ---------------------------------------------------------------------------
// MFMA flash attention (r14 internals: ring LDS, gload_lds, counted vmcnt,
// no-max softmax, setprio). r15: epilogue stores y TILED into yt so proj
// consumes it as direct-reg A. Tiled offset for (row,col):
// (row>>4)*16384 + (h*2 + (dt>>1))*512 + (lo + ((dt*2+(hi>>1))&3)*16)*8
// + (hi&1)*4.
// ---------------------------------------------------------------------------
__global__ __launch_bounds__(256) void attn3(
    const u16* __restrict__ q, const u16* __restrict__ k, const u16* __restrict__ vt,
    const float* __restrict__ gate, u16* __restrict__ yt) {
  __shared__ __attribute__((aligned(16))) unsigned char smem[49152];
  const int tid = threadIdx.x;
  const int wv = tid >> 6, lane = tid & 63, lo = lane & 15, hi = lane >> 4;
  const int raw = blockIdx.x;                  // 0..1023
  const int xcd = raw & 7;
  const int jj  = raw >> 3;                    // 0..127
  const int qt = 31 - (jj >> 2);               // 31..0
  const int bh = xcd * 4 + (jj & 3);           // 0..31
  const int b = bh >> 4, h = bh & 15;
  const int qb = qt << 6;

  const int qrow = b * T_ + qb + wv * 16 + lo;
  const u16* qp = q + (size_t)qrow * DIM_ + h * HD_;
  const bf16x8 qf0 = *(const bf16x8*)(qp + hi * 8);
  const bf16x8 qf1 = *(const bf16x8*)(qp + 32 + hi * 8);

  f32x4 o[4];
#pragma unroll
  for (int i = 0; i < 4; ++i) o[i] = (f32x4){0.f, 0.f, 0.f, 0.f};
  float lrun = 0.f;

  const int sl = tid & 63, skh = (tid >> 6) & 1, st0 = tid >> 7;
  const int srow = sl & 15, skk = skh * 32 + ((sl >> 4) << 3);
  const u16* kg0 = k + ((size_t)(b * T_ + st0 * 16 + srow)) * DIM_ + h * HD_ + skk;
  const u16* kg1 = kg0 + (size_t)32 * DIM_;
  const u16* vg0 = vt + ((size_t)(bh * HD_ + st0 * 16 + srow)) * T_ + skk;
  const u16* vg1 = vg0 + (size_t)32 * T_;
  const int wub = (tid >> 6) << 10;

  {
    gload_lds16(kg0, smem + wub);
    gload_lds16(kg1, smem + 4096 + wub);
    gload_lds16(vg0, smem + 8192 + wub);
    gload_lds16(vg1, smem + 12288 + wub);
    const int t1 = (qt >= 1) ? 1 : 0;
    const size_t ko = (size_t)t1 * 64 * DIM_;
    const size_t vo = (size_t)t1 * 64;
    unsigned char* b1 = smem + 16384;
    gload_lds16(kg0 + ko, b1 + wub);
    gload_lds16(kg1 + ko, b1 + 4096 + wub);
    gload_lds16(vg0 + vo, b1 + 8192 + wub);
    gload_lds16(vg1 + vo, b1 + 12288 + wub);
  }

  int sr = 0, sw = 2;
  for (int tix = 0; tix <= qt; ++tix) {
    __builtin_amdgcn_sched_barrier(0);
    if (tix < qt) {
      asm volatile("s_waitcnt vmcnt(4)" ::: "memory");
    } else {
      asm volatile("s_waitcnt vmcnt(0)" ::: "memory");
    }
    __builtin_amdgcn_s_barrier();
    __builtin_amdgcn_sched_barrier(0);
    if (tix + 2 <= qt) {
      const size_t ko = (size_t)(tix + 2) * 64 * DIM_;
      const size_t vo = (size_t)(tix + 2) * 64;
      unsigned char* base = smem + sw * 16384;
      gload_lds16(kg0 + ko, base + wub);
      gload_lds16(kg1 + ko, base + 4096 + wub);
      gload_lds16(vg0 + vo, base + 8192 + wub);
      gload_lds16(vg1 + vo, base + 12288 + wub);
    }
    const unsigned char* kb = smem + sr * 16384;
    const unsigned char* vb = kb + 8192;

    f32x4 stl[4];
#pragma unroll
    for (int kt = 0; kt < 4; ++kt) stl[kt] = (f32x4){0.f, 0.f, 0.f, 0.f};
    __builtin_amdgcn_s_setprio(1);
#pragma unroll
    for (int kh = 0; kh < 2; ++kh) {
      const bf16x8 qb_ = kh ? qf1 : qf0;
#pragma unroll
      for (int kt = 0; kt < 4; ++kt) {
        const bf16x8 af = *(const bf16x8*)(kb + (((kt * 2 + kh) * 64 + lane) << 4));
        stl[kt] = MFMA16(af, qb_, stl[kt]);
      }
    }
    __builtin_amdgcn_s_setprio(0);
    const bool diag = (tix == qt);
    float ps = 0.f;
#pragma unroll
    for (int kt = 0; kt < 4; ++kt)
#pragma unroll
      for (int r = 0; r < 4; ++r) {
        float s = stl[kt][r] * SCALE_;
        if (diag && (kt * 16 + hi * 4 + r > wv * 16 + lo)) s = -3e38f;
        const float e = __expf(s);
        stl[kt][r] = e;
        ps += e;
      }
    ps += __shfl_xor(ps, 16, 64);
    ps += __shfl_xor(ps, 32, 64);
    lrun += ps;

    u32 pkv[4][2];
#pragma unroll
    for (int kt = 0; kt < 4; ++kt) {
      pkv[kt][0] = pk2(stl[kt][0], stl[kt][1]);
      pkv[kt][1] = pk2(stl[kt][2], stl[kt][3]);
    }
#pragma unroll
    for (int kh = 0; kh < 2; ++kh) {
      uint4 w4;
      u32* w4p = (u32*)&w4;
#pragma unroll
      for (int wd = 0; wd < 4; ++wd) {
        const int src = (2 * (hi & 1) + (wd >> 1)) * 16 + lo;
        const u32 a  = (u32)__shfl((int)pkv[2 * kh][wd & 1], src, 64);
        const u32 bb = (u32)__shfl((int)pkv[2 * kh + 1][wd & 1], src, 64);
        w4p[wd] = (hi < 2) ? a : bb;
      }
      const bf16x8 pf = __builtin_bit_cast(bf16x8, w4);
      __builtin_amdgcn_s_setprio(1);
#pragma unroll
      for (int dt = 0; dt < 4; ++dt) {
        const bf16x8 vf = *(const bf16x8*)(vb + (((dt * 2 + kh) * 64 + lane) << 4));
        o[dt] = MFMA16(vf, pf, o[dt]);
      }
      __builtin_amdgcn_s_setprio(0);
    }
    sr = (sr == 2) ? 0 : sr + 1;
    sw = (sw == 2) ? 0 : sw + 1;
  }

  const float inv = gate[(size_t)qrow * H_ + h] / lrun;
  // tiled store of y: col = h*64 + dt*16 + hi*4
  u16* ybase = yt + (size_t)(qrow >> 4) * 16384 + (size_t)(h * 2) * 512
             + lo * 8 + (hi & 1) * 4;
#pragma unroll
  for (int dt = 0; dt < 4; ++dt) {
    ushort4 pq;
    pq.x = f2b(o[dt][0] * inv); pq.y = f2b(o[dt][1] * inv);
    pq.z = f2b(o[dt][2] * inv); pq.w = f2b(o[dt][3] * inv);
    const int c = (dt * 2 + (hi >> 1)) & 3;
    *(ushort4*)(ybase + (dt >> 1) * 512 + c * 128) = pq;
  }
}

// ---------------------------------------------------------------------------
extern "C" void kernel_launch(void* const* d_in, const int* in_sizes, int n_in,
                              void* d_out, int out_size, void* d_ws, size_t ws_size,
                              hipStream_t stream) {
  const float* x    = (const float*)d_in[0];
  const float* v1   = (const float*)d_in[1];
  const float* Wq   = (const float*)d_in[2];
  const float* Wk   = (const float*)d_in[3];
  const float* Wv   = (const float*)d_in[4];
  const float* Wp   = (const float*)d_in[5];
  const float* Wg   = (const float*)d_in[6];
  const float* lamb = (const float*)d_in[7];

  const size_t NX = (size_t)NROW * DIM_;        // 4M
  const size_t NW = (size_t)DIM_ * DIM_;        // 1M

  u16* q  = (u16*)d_ws;
  u16* k  = q + NX;
  u16* vt = k + NX;                             // [bh][d][t]
  u16* xb = vt + NX;                            // tiled x; later tiled y
  u16* wb = xb + NX;                            // tiled wq|wk|wv|wp (4M)
  float* gate = (float*)(wb + 4 * NW);          // total ws: 40.25 MB

  const dim3 bb(256);

  convert_all<<<dim3(4096), bb, 0, stream>>>(x, Wq, Wk, Wv, Wp, xb, wb);
  gemm_rp<false><<<dim3(768), bb, 0, stream>>>(
      xb, wb, q, k, vt, nullptr, v1, lamb);
  gate_kernel<<<dim3(NROW * H_ / 256), bb, 0, stream>>>(x, Wg, gate);
  attn3<<<dim3(1024), bb, 0, stream>>>(q, k, vt, gate, xb);
  gemm_rp<true><<<dim3(256), bb, 0, stream>>>(
      xb, wb + 3 * NW, nullptr, nullptr, nullptr, (float*)d_out, nullptr, nullptr);
}